// Round 17
// baseline (294.821 us; speedup 1.0000x reference)
//
#include <hip/hip_runtime.h>
#include <hip/hip_bf16.h>

#define NN 50000
#define NE 800000
#define NG 64
#define C1 128    // H1*D1
#define D2 32
#define NB 196    // (NN+255)/256 scan blocks
#define BN_EPS 1e-5f

// ---- constant-block layout (float offsets inside cst) ----
#define CST_A   0
#define CST_B   2
#define CST_P   4
#define CST_Q   132
#define CST_R   260
#define CST_SC2 388
#define CST_RC2 420
#define CST_SD  452
#define CST_RD  580
#define CST_N   1024

// ---- workspace layout (4-byte-unit offsets inside d_ws), total ~13.8 MiB ----
#define UO_DEG   0                        // int[NN]  (zeroed)
#define UO_CNT   50000                    // int[4]   (zeroed) scanA last-block counter
#define ZERO_UNITS 50004
#define UO_FLAG  50004                    // int[1]
#define UO_LOC   50008                    // int[NN]
#define UO_BSUM  100008                   // int[256]
#define UO_CARRY 100264                   // int[256]
#define UO_ESRC  100520                   // ushort[NE]  (node ids < 65536; 8B-aligned base)
#define UO_EOFF  500520                   // ushort[NE]  slot-within-node
#define UO_FCAN  900520                   // float[NN]
#define UO_CST   950520                   // float[CST_N]
#define UO_F2    951544                   // ushort[D2*NN] bf16 (16B aligned)
#define UO_RS2   1751544                  // float[D2*NN]; overwritten with h2 by k_final
#define UO_EL2   3351544                  // float[NN]
#define UO_ER2   3401544                  // float[NN]
#define UO_END   3451544

__device__ __forceinline__ float lrelu(float x) { return fmaxf(x, 0.2f * x); }
__device__ __forceinline__ float bu2f(unsigned int u) {
    union { unsigned int i; float f; } v; v.i = (u & 0xFFFFu) << 16; return v.f;
}
__device__ __forceinline__ unsigned short f2bu(float f) {
    union { float f; unsigned int i; } v; v.f = f;
    unsigned int r = v.i + 0x7FFFu + ((v.i >> 16) & 1u);
    return (unsigned short)(r >> 16);
}
__device__ __forceinline__ float pk_lo(unsigned int w) {
    union { unsigned int i; float f; } v; v.i = w << 16; return v.f;
}
__device__ __forceinline__ float pk_hi(unsigned int w) {
    union { unsigned int i; float f; } v; v.i = w & 0xFFFF0000u; return v.f;
}
__device__ __forceinline__ float ldw(const void* p, int i, int bf) {
    return bf ? bu2f(((const unsigned short*)p)[i]) : ((const float*)p)[i];
}
__device__ __forceinline__ int offat(const int* loc, const int* carry, int i) {
    return loc[i] + carry[i >> 8];
}
__device__ __forceinline__ int sniff64(const unsigned int* fw, int l) {
    int cnt = 0;
    for (int j = l; j < 256; j += 64) {
        unsigned int b = (fw[j] >> 8) & 0x7Fu;
        cnt += (b >= 0x3Au && b <= 0x41u) ? 1 : 0;
    }
#pragma unroll
    for (int m = 32; m >= 1; m >>= 1) cnt += __shfl_xor(cnt, m);
    return (cnt > 128) ? 1 : 0;
}

// ---------------- fcan convert + degree histogram (keeps slot) + (block 0) const folding ----------------
__global__ void k_prep(const void* __restrict__ feat, const int* __restrict__ dst,
                       float* __restrict__ fcan, int* __restrict__ deg,
                       unsigned short* __restrict__ eoff,
                       const void* W1, const void* al1, const void* ar1,
                       const void* res1, const void* b1,
                       const void* g1g, const void* g1b, const void* g1m, const void* g1v,
                       const void* b2v, const void* g2g, const void* g2b,
                       const void* g2m, const void* g2v,
                       const void* bd1, const void* gdg, const void* gdb,
                       const void* gdm, const void* gdv,
                       int* __restrict__ flag, float* __restrict__ cst) {
    __shared__ int sBf;
    int t = threadIdx.x;
    if (t < 64) {
        int bf = sniff64((const unsigned int*)feat, t);
        if (t == 0) sBf = bf;
    }
    __syncthreads();
    int bf = sBf;

    if (blockIdx.x == 0) {             // fold tiny weights into fp32 constants
        if (t == 0) *flag = bf;
        if (t < 128) {
            if (t < 2) {
                float a = 0.0f, b = 0.0f;
                for (int d = 0; d < 64; ++d) {
                    float w = ldw(W1, t * 64 + d, bf);
                    a += w * ldw(al1, t * 64 + d, bf);
                    b += w * ldw(ar1, t * 64 + d, bf);
                }
                cst[CST_A + t] = a;
                cst[CST_B + t] = b;
            }
            {
                float sc = rsqrtf(ldw(g1v, t, bf) + BN_EPS) * ldw(g1g, t, bf);
                cst[CST_P + t] = ldw(W1, t, bf) * sc;
                cst[CST_Q + t] = ldw(res1, t, bf) * sc;
                cst[CST_R + t] = (ldw(b1, t, bf) - ldw(g1m, t, bf)) * sc + ldw(g1b, t, bf);
            }
            if (t < D2) {
                float sc = rsqrtf(ldw(g2v, t, bf) + BN_EPS) * ldw(g2g, t, bf);
                cst[CST_SC2 + t] = sc;
                cst[CST_RC2 + t] = (ldw(b2v, t, bf) - ldw(g2m, t, bf)) * sc + ldw(g2b, t, bf);
            }
            {
                float sc = rsqrtf(ldw(gdv, t, bf) + BN_EPS) * ldw(gdg, t, bf);
                cst[CST_SD + t] = sc;
                cst[CST_RD + t] = (ldw(bd1, t, bf) - ldw(gdm, t, bf)) * sc + ldw(gdb, t, bf);
            }
        }
    }

    int k = blockIdx.x * blockDim.x + t;
    if (k < NN) fcan[k] = ldw(feat, k, bf);
    if (k < NE) eoff[k] = (unsigned short)atomicAdd(&deg[dst[k]], 1);
}

// ---------------- scan: per-block exclusive scan + last-block does the carry scan ----------------
__global__ __launch_bounds__(256) void k_scanA(const int* __restrict__ deg,
                                               int* __restrict__ loc,
                                               int* __restrict__ bsum,
                                               int* __restrict__ carry,
                                               int* __restrict__ cnt) {
    __shared__ int tmp[256];
    __shared__ int isLast;
    int t = threadIdx.x;
    int i = blockIdx.x * 256 + t;
    int v = (i < NN) ? deg[i] : 0;
    tmp[t] = v;
    __syncthreads();
    for (int off = 1; off < 256; off <<= 1) {
        int u = (t >= off) ? tmp[t - off] : 0;
        __syncthreads();
        tmp[t] += u;
        __syncthreads();
    }
    if (i < NN) loc[i] = tmp[t] - v;
    if (t == 255) {
        bsum[blockIdx.x] = tmp[255];
        __threadfence();
        int old = atomicAdd(cnt, 1);
        isLast = (old == NB - 1) ? 1 : 0;
    }
    __syncthreads();
    if (isLast) {
        __threadfence();
        int bv = (t < NB) ? bsum[t] : 0;
        tmp[t] = bv;
        __syncthreads();
        for (int off = 1; off < 256; off <<= 1) {
            int u = (t >= off) ? tmp[t - off] : 0;
            __syncthreads();
            tmp[t] += u;
            __syncthreads();
        }
        carry[t] = tmp[t] - bv;
    }
}

// ---------------- CSR fill: atomic-free, ushort payload ----------------
__global__ void k_fill(const int* __restrict__ src, const int* __restrict__ dst,
                       const int* __restrict__ loc, const int* __restrict__ carry,
                       const unsigned short* __restrict__ eoff,
                       unsigned short* __restrict__ esrc) {
    int k = blockIdx.x * blockDim.x + threadIdx.x;
    if (k >= NE) return;
    int d = dst[k];
    esrc[offat(loc, carry, d) + (int)eoff[k]] = (unsigned short)src[k];
}

// ---------------- layer-1: 32 nodes/block; interleaved phase-1 chains + packed projection ----------------
__global__ __launch_bounds__(256) void k_layer1(
        const float* __restrict__ fcan, const void* W2, const void* res2,
        const void* al2, const void* ar2,
        const int* __restrict__ flag, const float* __restrict__ cst,
        const int* __restrict__ loc, const int* __restrict__ carry,
        const unsigned short* __restrict__ esrc,
        unsigned short* __restrict__ F2, float* __restrict__ RS2,
        float* __restrict__ EL2, float* __restrict__ ER2) {
    __shared__ unsigned int sW2pk[32 * 66];  // [l][cw], (c,c+64) bf16 pairs
    __shared__ unsigned int sR2pk[32 * 66];
    __shared__ unsigned int sH1pk[32 * 66];
    __shared__ float sP[C1], sQ[C1], sR[C1];
    __shared__ float sAl[D2], sAr[D2];
    int t = threadIdx.x;
    int bf = *flag;
    for (int u = t; u < 2048; u += 256) {
        int cw = u >> 5, l2 = u & 31;
        unsigned int wlo = (unsigned int)f2bu(ldw(W2, cw * D2 + l2, bf));
        unsigned int whi = (unsigned int)f2bu(ldw(W2, (cw + 64) * D2 + l2, bf));
        sW2pk[l2 * 66 + cw] = wlo | (whi << 16);
        unsigned int rlo = (unsigned int)f2bu(ldw(res2, cw * D2 + l2, bf));
        unsigned int rhi = (unsigned int)f2bu(ldw(res2, (cw + 64) * D2 + l2, bf));
        sR2pk[l2 * 66 + cw] = rlo | (rhi << 16);
    }
    if (t < C1) { sP[t] = cst[CST_P + t]; sQ[t] = cst[CST_Q + t]; sR[t] = cst[CST_R + t]; }
    if (t < D2) { sAl[t] = ldw(al2, t, bf); sAr[t] = ldw(ar2, t, bf); }
    __syncthreads();

    int l = t & 31;
    int g = t >> 5;
    int base = blockIdx.x * 32;
    float A0 = cst[CST_A + 0], A1 = cst[CST_A + 1];
    float B0 = cst[CST_B + 0], B1 = cst[CST_B + 1];

    int e0k[4], e1k[4];
    float fiK[4];
#pragma unroll
    for (int k = 0; k < 4; ++k) {
        int i = base + g * 4 + k;
        if (i < NN) {
            e0k[k] = offat(loc, carry, i);
            e1k[k] = (i + 1 < NN) ? offat(loc, carry, i + 1) : NE;
            fiK[k] = fcan[i];
        } else { e0k[k] = 0; e1k[k] = 0; fiK[k] = 0.0f; }
    }
    float S0[4], S1[4], N0[4], N1[4];
#pragma unroll
    for (int k = 0; k < 4; ++k) { S0[k] = S1[k] = N0[k] = N1[k] = 0.0f; }
    int sA[4];
#pragma unroll
    for (int k = 0; k < 4; ++k) sA[k] = (e0k[k] + l < e1k[k]) ? (int)esrc[e0k[k] + l] : 0;
    float fA[4];
#pragma unroll
    for (int k = 0; k < 4; ++k) fA[k] = fcan[sA[k]];
#pragma unroll
    for (int k = 0; k < 4; ++k) {
        if (e0k[k] + l < e1k[k]) {
            float w0 = __expf(lrelu(A0 * fA[k] + B0 * fiK[k]));
            float w1 = __expf(lrelu(A1 * fA[k] + B1 * fiK[k]));
            S0[k] += w0; N0[k] += w0 * fA[k];
            S1[k] += w1; N1[k] += w1 * fA[k];
        }
    }
#pragma unroll
    for (int k = 0; k < 4; ++k) {
        for (int e = e0k[k] + l + 32; e < e1k[k]; e += 32) {
            int s = (int)esrc[e];
            float fs = fcan[s];
            float w0 = __expf(lrelu(A0 * fs + B0 * fiK[k]));
            float w1 = __expf(lrelu(A1 * fs + B1 * fiK[k]));
            S0[k] += w0; N0[k] += w0 * fs;
            S1[k] += w1; N1[k] += w1 * fs;
        }
    }
#pragma unroll
    for (int m = 16; m >= 1; m >>= 1) {
#pragma unroll
        for (int k = 0; k < 4; ++k) {
            S0[k] += __shfl_xor(S0[k], m); N0[k] += __shfl_xor(N0[k], m);
            S1[k] += __shfl_xor(S1[k], m); N1[k] += __shfl_xor(N1[k], m);
        }
    }
#pragma unroll
    for (int k = 0; k < 4; ++k) {
        int slot = g * 4 + k;
        float T0 = S0[k] > 0.0f ? N0[k] / S0[k] : 0.0f;
        float T1 = S1[k] > 0.0f ? N1[k] / S1[k] : 0.0f;
        float h0  = fmaxf(sP[l]      * T0 + sQ[l]      * fiK[k] + sR[l],      0.0f);
        float h1v = fmaxf(sP[l + 32] * T0 + sQ[l + 32] * fiK[k] + sR[l + 32], 0.0f);
        float h2v = fmaxf(sP[l + 64] * T1 + sQ[l + 64] * fiK[k] + sR[l + 64], 0.0f);
        float h3v = fmaxf(sP[l + 96] * T1 + sQ[l + 96] * fiK[k] + sR[l + 96], 0.0f);
        sH1pk[slot * 66 + l]      = (unsigned int)f2bu(h0)  | ((unsigned int)f2bu(h2v) << 16);
        sH1pk[slot * 66 + l + 32] = (unsigned int)f2bu(h1v) | ((unsigned int)f2bu(h3v) << 16);
    }
    __syncthreads();

    int w = t >> 6;
    int half = (t >> 5) & 1;
    int nb0 = w * 8 + half * 4;
    float aF[4] = {0.f, 0.f, 0.f, 0.f}, aR[4] = {0.f, 0.f, 0.f, 0.f};
    for (int cw = 0; cw < 64; cw += 2) {
        uint2 wq = *(const uint2*)&sW2pk[l * 66 + cw];
        uint2 rq = *(const uint2*)&sR2pk[l * 66 + cw];
        float w_a = pk_lo(wq.x), w_b = pk_hi(wq.x), w_c = pk_lo(wq.y), w_d = pk_hi(wq.y);
        float r_a = pk_lo(rq.x), r_b = pk_hi(rq.x), r_c = pk_lo(rq.y), r_d = pk_hi(rq.y);
#pragma unroll
        for (int n = 0; n < 4; ++n) {
            uint2 hq = *(const uint2*)&sH1pk[(nb0 + n) * 66 + cw];
            float h_a = pk_lo(hq.x), h_b = pk_hi(hq.x), h_c = pk_lo(hq.y), h_d = pk_hi(hq.y);
            aF[n] = fmaf(h_a, w_a, fmaf(h_b, w_b, fmaf(h_c, w_c, fmaf(h_d, w_d, aF[n]))));
            aR[n] = fmaf(h_a, r_a, fmaf(h_b, r_b, fmaf(h_c, r_c, fmaf(h_d, r_d, aR[n]))));
        }
    }
#pragma unroll
    for (int n = 0; n < 4; ++n) {
        int i = base + nb0 + n;
        if (i < NN) {
            float elp = aF[n] * sAl[l], erp = aF[n] * sAr[l];
#pragma unroll
            for (int m = 16; m >= 1; m >>= 1) {
                elp += __shfl_xor(elp, m);
                erp += __shfl_xor(erp, m);
            }
            if (l == 0) { EL2[i] = elp; ER2[i] = erp; }
            F2[(size_t)i * D2 + l]  = f2bu(aF[n]);
            RS2[(size_t)i * D2 + l] = aR[n];
        }
    }
}

// ---------------- layer-2 gather (ushort4 edge loads, 4 chains) + BN2/ReLU + reordered decoder ----------------
__global__ __launch_bounds__(256) void k_final(
        const void* Wd1, const void* Wd2, const void* bd2,
        const int* __restrict__ flag, const float* __restrict__ cst,
        const int* __restrict__ loc, const int* __restrict__ carry,
        const unsigned short* __restrict__ esrc,
        const unsigned short* __restrict__ F2, float* __restrict__ RS2,
        const float* __restrict__ EL2, const float* __restrict__ ER2,
        float* __restrict__ out) {
    __shared__ float sWd1[C1 * D2];
    __shared__ float sWd2[C1];
    __shared__ float sSd[C1], sRd[C1];
    __shared__ float sSc2[D2], sRc2[D2];
    __shared__ float sH2[8 * D2];
    int t = threadIdx.x;
    int bf = *flag;
    for (int u = t; u < C1 * D2; u += 256) sWd1[u] = ldw(Wd1, u, bf);
    for (int u = t; u < C1; u += 256) {
        sWd2[u] = ldw(Wd2, u, bf);
        sSd[u] = cst[CST_SD + u]; sRd[u] = cst[CST_RD + u];
    }
    if (t < D2) { sSc2[t] = cst[CST_SC2 + t]; sRc2[t] = cst[CST_RC2 + t]; }
    __syncthreads();

    int i = (blockIdx.x * 256 + t) >> 5;
    int l = t & 31;
    int nb = t >> 5;

    float eri = ER2[i];
    int e0 = offat(loc, carry, i);
    int e1 = (i + 1 < NN) ? offat(loc, carry, i + 1) : NE;
    float aF0 = 0.0f, aF1 = 0.0f, aF2 = 0.0f, aF3 = 0.0f;
    float S0 = 0.0f, S1 = 0.0f, S2 = 0.0f, S3 = 0.0f;
    int e = e0;
    // prologue: align e to 4 for ushort4 loads (esrc base is 8B-aligned)
    for (; e < e1 && (e & 3); ++e) {
        int sA = (int)esrc[e];
        float wA = __expf(lrelu(EL2[sA] + eri));
        S0 += wA;
        aF0 = fmaf(wA, bu2f(F2[(size_t)sA * D2 + l]), aF0);
    }
    for (; e + 3 < e1; e += 4) {
        ushort4 q = *(const ushort4*)&esrc[e];   // 4 edge ids, one load
        int sA = q.x, sB = q.y, sC = q.z, sD = q.w;
        float wA = __expf(lrelu(EL2[sA] + eri));
        float wB = __expf(lrelu(EL2[sB] + eri));
        float wC = __expf(lrelu(EL2[sC] + eri));
        float wD = __expf(lrelu(EL2[sD] + eri));
        float vA = bu2f(F2[(size_t)sA * D2 + l]);
        float vB = bu2f(F2[(size_t)sB * D2 + l]);
        float vC = bu2f(F2[(size_t)sC * D2 + l]);
        float vD = bu2f(F2[(size_t)sD * D2 + l]);
        S0 += wA; S1 += wB; S2 += wC; S3 += wD;
        aF0 = fmaf(wA, vA, aF0);
        aF1 = fmaf(wB, vB, aF1);
        aF2 = fmaf(wC, vC, aF2);
        aF3 = fmaf(wD, vD, aF3);
    }
    for (; e < e1; ++e) {
        int sA = (int)esrc[e];
        float wA = __expf(lrelu(EL2[sA] + eri));
        S0 += wA;
        aF0 = fmaf(wA, bu2f(F2[(size_t)sA * D2 + l]), aF0);
    }
    float S = (S0 + S1) + (S2 + S3);
    float aF = (aF0 + aF1) + (aF2 + aF3);
    float inv = S > 0.0f ? 1.0f / S : 0.0f;

    float h2 = fmaxf((aF * inv + RS2[(size_t)i * D2 + l]) * sSc2[l] + sRc2[l], 0.0f);
    RS2[(size_t)i * D2 + l] = h2;

    // --- decoder, d-outer loop: sH2 read once per d (160 LDS reads vs 256)
    sH2[nb * D2 + l] = h2;
    float ac0 = 0.0f, ac1 = 0.0f, ac2 = 0.0f, ac3 = 0.0f;
#pragma unroll
    for (int d = 0; d < D2; ++d) {
        float h = sH2[nb * D2 + d];               // broadcast
        const float* wr = &sWd1[d * C1 + l];
        ac0 = fmaf(h, wr[0],  ac0);
        ac1 = fmaf(h, wr[32], ac1);
        ac2 = fmaf(h, wr[64], ac2);
        ac3 = fmaf(h, wr[96], ac3);
    }
    float rec = fmaxf(ac0 * sSd[l]      + sRd[l],      0.0f) * sWd2[l]
              + fmaxf(ac1 * sSd[l + 32] + sRd[l + 32], 0.0f) * sWd2[l + 32]
              + fmaxf(ac2 * sSd[l + 64] + sRd[l + 64], 0.0f) * sWd2[l + 64]
              + fmaxf(ac3 * sSd[l + 96] + sRd[l + 96], 0.0f) * sWd2[l + 96];
#pragma unroll
    for (int m = 16; m >= 1; m >>= 1) rec += __shfl_xor(rec, m);
    if (l == 0) out[NG * D2 + i] = rec + ldw(bd2, 0, bf);
}

// ---------------- graph mean pool: one block per graph, zero atomics ----------------
__global__ __launch_bounds__(256) void k_pool2(const int* __restrict__ gid,
                                               const float* __restrict__ H2,
                                               float* __restrict__ out) {
    __shared__ int sLo, sHi;
    __shared__ float sAcc[8 * D2];
    int g = blockIdx.x;
    int t = threadIdx.x;
    if (t == 0) {
        int lo = 0, hi = NN;
        while (lo < hi) { int m = (lo + hi) >> 1; if (gid[m] < g) lo = m + 1; else hi = m; }
        sLo = lo;
        lo = 0; hi = NN;
        while (lo < hi) { int m = (lo + hi) >> 1; if (gid[m] < g + 1) lo = m + 1; else hi = m; }
        sHi = lo;
    }
    __syncthreads();
    int lo = sLo, hi = sHi;
    int l = t & 31, row = t >> 5;
    float acc = 0.0f;
    for (int i = lo + row; i < hi; i += 8)
        acc += H2[(size_t)i * D2 + l];
    sAcc[row * D2 + l] = acc;
    __syncthreads();
    if (row == 0) {
#pragma unroll
        for (int r = 1; r < 8; ++r) acc += sAcc[r * D2 + l];
        float c = (float)(hi - lo);
        out[g * D2 + l] = acc / fmaxf(c, 1.0f);
    }
}

extern "C" void kernel_launch(void* const* d_in, const int* in_sizes, int n_in,
                              void* d_out, int out_size, void* d_ws, size_t ws_size,
                              hipStream_t stream) {
    const void* feat = d_in[0];
    const void* W1 = d_in[1];  const void* al1 = d_in[2];  const void* ar1 = d_in[3];
    const void* res1 = d_in[4]; const void* b1 = d_in[5];
    const void* g1g = d_in[6]; const void* g1b = d_in[7];
    const void* g1m = d_in[8]; const void* g1v = d_in[9];
    const void* W2 = d_in[10]; const void* al2 = d_in[11]; const void* ar2 = d_in[12];
    const void* res2 = d_in[13]; const void* b2v = d_in[14];
    const void* g2g = d_in[15]; const void* g2b = d_in[16];
    const void* g2m = d_in[17]; const void* g2v = d_in[18];
    const void* Wd1 = d_in[19]; const void* bd1 = d_in[20];
    const void* gdg = d_in[21]; const void* gdb = d_in[22];
    const void* gdm = d_in[23]; const void* gdv = d_in[24];
    const void* Wd2 = d_in[25]; const void* bd2 = d_in[26];
    const int* src = (const int*)d_in[27];
    const int* dst = (const int*)d_in[28];
    const int* gid = (const int*)d_in[29];

    unsigned int* wsu = (unsigned int*)d_ws;
    int* deg    = (int*)(wsu + UO_DEG);
    int* cnt    = (int*)(wsu + UO_CNT);
    int* flag   = (int*)(wsu + UO_FLAG);
    int* loc    = (int*)(wsu + UO_LOC);
    int* bsum   = (int*)(wsu + UO_BSUM);
    int* carry  = (int*)(wsu + UO_CARRY);
    unsigned short* esrc = (unsigned short*)(wsu + UO_ESRC);
    unsigned short* eoff = (unsigned short*)(wsu + UO_EOFF);
    float* fcan = (float*)(wsu + UO_FCAN);
    float* cst  = (float*)(wsu + UO_CST);
    unsigned short* F2 = (unsigned short*)(wsu + UO_F2);
    float* RS2  = (float*)(wsu + UO_RS2);
    float* EL2  = (float*)(wsu + UO_EL2);
    float* ER2  = (float*)(wsu + UO_ER2);

    hipMemsetAsync(d_ws, 0, (size_t)ZERO_UNITS * 4, stream);

    k_prep<<<(NE + 255) / 256, 256, 0, stream>>>(feat, dst, fcan, deg, eoff,
                                                 W1, al1, ar1, res1, b1,
                                                 g1g, g1b, g1m, g1v,
                                                 b2v, g2g, g2b, g2m, g2v,
                                                 bd1, gdg, gdb, gdm, gdv,
                                                 flag, cst);
    k_scanA<<<NB, 256, 0, stream>>>(deg, loc, bsum, carry, cnt);
    k_fill<<<(NE + 255) / 256, 256, 0, stream>>>(src, dst, loc, carry, eoff, esrc);

    k_layer1<<<(NN + 31) / 32, 256, 0, stream>>>(fcan, W2, res2, al2, ar2, flag, cst,
                                                 loc, carry, esrc, F2, RS2, EL2, ER2);

    k_final<<<(NN * 32) / 256, 256, 0, stream>>>(Wd1, Wd2, bd2, flag, cst,
                                                 loc, carry, esrc, F2, RS2, EL2, ER2,
                                                 (float*)d_out);

    k_pool2<<<NG, 256, 0, stream>>>(gid, RS2, (float*)d_out);
}

// Round 18
// 275.981 us; speedup vs baseline: 1.0683x; 1.0683x over previous
//
#include <hip/hip_runtime.h>
#include <hip/hip_bf16.h>

#define NN 50000
#define NE 800000
#define NG 64
#define C1 128    // H1*D1
#define D2 32
#define CAP 32    // capped slots per node; overflow handled exactly via ovf buffer
#define BN_EPS 1e-5f

// ---- constant-block layout (float offsets inside cst) ----
#define CST_A   0
#define CST_B   2
#define CST_P   4
#define CST_Q   132
#define CST_R   260
#define CST_SC2 388
#define CST_RC2 420
#define CST_SD  452
#define CST_RD  580
#define CST_N   1024

// ---- workspace layout (4-byte-unit offsets inside d_ws), ~20 MiB (ws is 256 MB) ----
#define UO_DEG   0                        // int[NN]  (zeroed)
#define UO_OVFC  50000                    // int[1]   (zeroed) overflow counter
#define ZERO_UNITS 50004
#define UO_FLAG  50004                    // int[1]
#define UO_CST   50008                    // float[CST_N]
#define UO_ESRC2 51040                    // ushort[CAP*NN] padded edge table (64B-aligned rows)
#define UO_OVF   851040                   // int2[NE] overflow (dst,src) — unconditional correctness
#define UO_FCAN  2451040                  // float[NN]
#define UO_F2    2501040                  // ushort[D2*NN] bf16 (16B aligned)
#define UO_RS2   3301040                  // float[D2*NN]; overwritten with h2 by k_final
#define UO_EL2   4901040                  // float[NN]
#define UO_ER2   4951040                  // float[NN]
#define UO_END   5001040

__device__ __forceinline__ float lrelu(float x) { return fmaxf(x, 0.2f * x); }
__device__ __forceinline__ float bu2f(unsigned int u) {
    union { unsigned int i; float f; } v; v.i = (u & 0xFFFFu) << 16; return v.f;
}
__device__ __forceinline__ unsigned short f2bu(float f) {
    union { float f; unsigned int i; } v; v.f = f;
    unsigned int r = v.i + 0x7FFFu + ((v.i >> 16) & 1u);
    return (unsigned short)(r >> 16);
}
__device__ __forceinline__ float pk_lo(unsigned int w) {
    union { unsigned int i; float f; } v; v.i = w << 16; return v.f;
}
__device__ __forceinline__ float pk_hi(unsigned int w) {
    union { unsigned int i; float f; } v; v.i = w & 0xFFFF0000u; return v.f;
}
__device__ __forceinline__ float ldw(const void* p, int i, int bf) {
    return bf ? bu2f(((const unsigned short*)p)[i]) : ((const float*)p)[i];
}
__device__ __forceinline__ int sniff64(const unsigned int* fw, int l) {
    int cnt = 0;
    for (int j = l; j < 256; j += 64) {
        unsigned int b = (fw[j] >> 8) & 0x7Fu;
        cnt += (b >= 0x3Au && b <= 0x41u) ? 1 : 0;
    }
#pragma unroll
    for (int m = 32; m >= 1; m >>= 1) cnt += __shfl_xor(cnt, m);
    return (cnt > 128) ? 1 : 0;
}

// ---------------- fcan + capped edge-table build + (block 0) const folding ----------------
__global__ void k_prep(const void* __restrict__ feat, const int* __restrict__ dst,
                       const int* __restrict__ src,
                       float* __restrict__ fcan, int* __restrict__ deg,
                       unsigned short* __restrict__ esrc2,
                       int2* __restrict__ ovf, int* __restrict__ ovfc,
                       const void* W1, const void* al1, const void* ar1,
                       const void* res1, const void* b1,
                       const void* g1g, const void* g1b, const void* g1m, const void* g1v,
                       const void* b2v, const void* g2g, const void* g2b,
                       const void* g2m, const void* g2v,
                       const void* bd1, const void* gdg, const void* gdb,
                       const void* gdm, const void* gdv,
                       int* __restrict__ flag, float* __restrict__ cst) {
    __shared__ int sBf;
    int t = threadIdx.x;
    if (t < 64) {
        int bf = sniff64((const unsigned int*)feat, t);
        if (t == 0) sBf = bf;
    }
    __syncthreads();
    int bf = sBf;

    if (blockIdx.x == 0) {             // fold tiny weights into fp32 constants
        if (t == 0) *flag = bf;
        if (t < 128) {
            if (t < 2) {
                float a = 0.0f, b = 0.0f;
                for (int d = 0; d < 64; ++d) {
                    float w = ldw(W1, t * 64 + d, bf);
                    a += w * ldw(al1, t * 64 + d, bf);
                    b += w * ldw(ar1, t * 64 + d, bf);
                }
                cst[CST_A + t] = a;
                cst[CST_B + t] = b;
            }
            {
                float sc = rsqrtf(ldw(g1v, t, bf) + BN_EPS) * ldw(g1g, t, bf);
                cst[CST_P + t] = ldw(W1, t, bf) * sc;
                cst[CST_Q + t] = ldw(res1, t, bf) * sc;
                cst[CST_R + t] = (ldw(b1, t, bf) - ldw(g1m, t, bf)) * sc + ldw(g1b, t, bf);
            }
            if (t < D2) {
                float sc = rsqrtf(ldw(g2v, t, bf) + BN_EPS) * ldw(g2g, t, bf);
                cst[CST_SC2 + t] = sc;
                cst[CST_RC2 + t] = (ldw(b2v, t, bf) - ldw(g2m, t, bf)) * sc + ldw(g2b, t, bf);
            }
            {
                float sc = rsqrtf(ldw(gdv, t, bf) + BN_EPS) * ldw(gdg, t, bf);
                cst[CST_SD + t] = sc;
                cst[CST_RD + t] = (ldw(bd1, t, bf) - ldw(gdm, t, bf)) * sc + ldw(gdb, t, bf);
            }
        }
    }

    int k = blockIdx.x * blockDim.x + t;
    if (k < NN) fcan[k] = ldw(feat, k, bf);
    if (k < NE) {
        int d = dst[k];
        int slot = atomicAdd(&deg[d], 1);
        if (slot < CAP) {
            esrc2[d * CAP + slot] = (unsigned short)src[k];
        } else {
            int p = atomicAdd(ovfc, 1);           // rare (~tens of edges)
            ovf[p] = make_int2(d, src[k]);
        }
    }
}

// ---------------- layer-1: 32 nodes/block; single-chunk gather + packed projection ----------------
__global__ __launch_bounds__(256) void k_layer1(
        const float* __restrict__ fcan, const void* W2, const void* res2,
        const void* al2, const void* ar2,
        const int* __restrict__ flag, const float* __restrict__ cst,
        const int* __restrict__ deg, const unsigned short* __restrict__ esrc2,
        const int2* __restrict__ ovf, const int* __restrict__ ovfc,
        unsigned short* __restrict__ F2, float* __restrict__ RS2,
        float* __restrict__ EL2, float* __restrict__ ER2) {
    __shared__ unsigned int sW2pk[32 * 66];  // [l][cw], (c,c+64) bf16 pairs
    __shared__ unsigned int sR2pk[32 * 66];
    __shared__ unsigned int sH1pk[32 * 66];
    __shared__ float sP[C1], sQ[C1], sR[C1];
    __shared__ float sAl[D2], sAr[D2];
    int t = threadIdx.x;
    int bf = *flag;
    for (int u = t; u < 2048; u += 256) {
        int cw = u >> 5, l2 = u & 31;
        unsigned int wlo = (unsigned int)f2bu(ldw(W2, cw * D2 + l2, bf));
        unsigned int whi = (unsigned int)f2bu(ldw(W2, (cw + 64) * D2 + l2, bf));
        sW2pk[l2 * 66 + cw] = wlo | (whi << 16);
        unsigned int rlo = (unsigned int)f2bu(ldw(res2, cw * D2 + l2, bf));
        unsigned int rhi = (unsigned int)f2bu(ldw(res2, (cw + 64) * D2 + l2, bf));
        sR2pk[l2 * 66 + cw] = rlo | (rhi << 16);
    }
    if (t < C1) { sP[t] = cst[CST_P + t]; sQ[t] = cst[CST_Q + t]; sR[t] = cst[CST_R + t]; }
    if (t < D2) { sAl[t] = ldw(al2, t, bf); sAr[t] = ldw(ar2, t, bf); }
    __syncthreads();

    int l = t & 31;
    int g = t >> 5;
    int base = blockIdx.x * 32;
    float A0 = cst[CST_A + 0], A1 = cst[CST_A + 1];
    float B0 = cst[CST_B + 0], B1 = cst[CST_B + 1];

    int dcap[4], draw[4];
    float fiK[4];
#pragma unroll
    for (int k = 0; k < 4; ++k) {
        int i = base + g * 4 + k;
        if (i < NN) {
            draw[k] = deg[i];
            dcap[k] = draw[k] < CAP ? draw[k] : CAP;
            fiK[k] = fcan[i];
        } else { draw[k] = 0; dcap[k] = 0; fiK[k] = 0.0f; }
    }
    float S0[4], S1[4], N0[4], N1[4];
#pragma unroll
    for (int k = 0; k < 4; ++k) { S0[k] = S1[k] = N0[k] = N1[k] = 0.0f; }
    // single chunk: lane l = slot l (contiguous 64B row per node), 4 chains interleaved
    int sA[4];
#pragma unroll
    for (int k = 0; k < 4; ++k)
        sA[k] = (l < dcap[k]) ? (int)esrc2[(base + g * 4 + k) * CAP + l] : 0;
    float fA[4];
#pragma unroll
    for (int k = 0; k < 4; ++k) fA[k] = fcan[sA[k]];
#pragma unroll
    for (int k = 0; k < 4; ++k) {
        if (l < dcap[k]) {
            float w0 = __expf(lrelu(A0 * fA[k] + B0 * fiK[k]));
            float w1 = __expf(lrelu(A1 * fA[k] + B1 * fiK[k]));
            S0[k] += w0; N0[k] += w0 * fA[k];
            S1[k] += w1; N1[k] += w1 * fA[k];
        }
    }
    // rare overflow edges (deg > CAP): lane-strided scan of the tiny global list
#pragma unroll
    for (int k = 0; k < 4; ++k) {
        if (draw[k] > CAP) {
            int i = base + g * 4 + k;
            int novf = *ovfc;
            for (int p = l; p < novf; p += 32) {
                int2 o = ovf[p];
                if (o.x == i) {
                    float fs = fcan[o.y];
                    float w0 = __expf(lrelu(A0 * fs + B0 * fiK[k]));
                    float w1 = __expf(lrelu(A1 * fs + B1 * fiK[k]));
                    S0[k] += w0; N0[k] += w0 * fs;
                    S1[k] += w1; N1[k] += w1 * fs;
                }
            }
        }
    }
#pragma unroll
    for (int m = 16; m >= 1; m >>= 1) {
#pragma unroll
        for (int k = 0; k < 4; ++k) {
            S0[k] += __shfl_xor(S0[k], m); N0[k] += __shfl_xor(N0[k], m);
            S1[k] += __shfl_xor(S1[k], m); N1[k] += __shfl_xor(N1[k], m);
        }
    }
#pragma unroll
    for (int k = 0; k < 4; ++k) {
        int slot = g * 4 + k;
        float T0 = S0[k] > 0.0f ? N0[k] / S0[k] : 0.0f;
        float T1 = S1[k] > 0.0f ? N1[k] / S1[k] : 0.0f;
        float h0  = fmaxf(sP[l]      * T0 + sQ[l]      * fiK[k] + sR[l],      0.0f);
        float h1v = fmaxf(sP[l + 32] * T0 + sQ[l + 32] * fiK[k] + sR[l + 32], 0.0f);
        float h2v = fmaxf(sP[l + 64] * T1 + sQ[l + 64] * fiK[k] + sR[l + 64], 0.0f);
        float h3v = fmaxf(sP[l + 96] * T1 + sQ[l + 96] * fiK[k] + sR[l + 96], 0.0f);
        sH1pk[slot * 66 + l]      = (unsigned int)f2bu(h0)  | ((unsigned int)f2bu(h2v) << 16);
        sH1pk[slot * 66 + l + 32] = (unsigned int)f2bu(h1v) | ((unsigned int)f2bu(h3v) << 16);
    }
    __syncthreads();

    int w = t >> 6;
    int half = (t >> 5) & 1;
    int nb0 = w * 8 + half * 4;
    float aF[4] = {0.f, 0.f, 0.f, 0.f}, aR[4] = {0.f, 0.f, 0.f, 0.f};
    for (int cw = 0; cw < 64; cw += 2) {
        uint2 wq = *(const uint2*)&sW2pk[l * 66 + cw];
        uint2 rq = *(const uint2*)&sR2pk[l * 66 + cw];
        float w_a = pk_lo(wq.x), w_b = pk_hi(wq.x), w_c = pk_lo(wq.y), w_d = pk_hi(wq.y);
        float r_a = pk_lo(rq.x), r_b = pk_hi(rq.x), r_c = pk_lo(rq.y), r_d = pk_hi(rq.y);
#pragma unroll
        for (int n = 0; n < 4; ++n) {
            uint2 hq = *(const uint2*)&sH1pk[(nb0 + n) * 66 + cw];
            float h_a = pk_lo(hq.x), h_b = pk_hi(hq.x), h_c = pk_lo(hq.y), h_d = pk_hi(hq.y);
            aF[n] = fmaf(h_a, w_a, fmaf(h_b, w_b, fmaf(h_c, w_c, fmaf(h_d, w_d, aF[n]))));
            aR[n] = fmaf(h_a, r_a, fmaf(h_b, r_b, fmaf(h_c, r_c, fmaf(h_d, r_d, aR[n]))));
        }
    }
#pragma unroll
    for (int n = 0; n < 4; ++n) {
        int i = base + nb0 + n;
        if (i < NN) {
            float elp = aF[n] * sAl[l], erp = aF[n] * sAr[l];
#pragma unroll
            for (int m = 16; m >= 1; m >>= 1) {
                elp += __shfl_xor(elp, m);
                erp += __shfl_xor(erp, m);
            }
            if (l == 0) { EL2[i] = elp; ER2[i] = erp; }
            F2[(size_t)i * D2 + l]  = f2bu(aF[n]);
            RS2[(size_t)i * D2 + l] = aR[n];
        }
    }
}

// ---------------- layer-2 gather (contiguous capped rows) + BN2/ReLU + decoder ----------------
__global__ __launch_bounds__(256) void k_final(
        const void* Wd1, const void* Wd2, const void* bd2,
        const int* __restrict__ flag, const float* __restrict__ cst,
        const int* __restrict__ deg, const unsigned short* __restrict__ esrc2,
        const int2* __restrict__ ovf, const int* __restrict__ ovfc,
        const unsigned short* __restrict__ F2, float* __restrict__ RS2,
        const float* __restrict__ EL2, const float* __restrict__ ER2,
        float* __restrict__ out) {
    __shared__ float sWd1[C1 * D2];
    __shared__ float sWd2[C1];
    __shared__ float sSd[C1], sRd[C1];
    __shared__ float sSc2[D2], sRc2[D2];
    __shared__ float sH2[8 * D2];
    int t = threadIdx.x;
    int bf = *flag;
    for (int u = t; u < C1 * D2; u += 256) sWd1[u] = ldw(Wd1, u, bf);
    for (int u = t; u < C1; u += 256) {
        sWd2[u] = ldw(Wd2, u, bf);
        sSd[u] = cst[CST_SD + u]; sRd[u] = cst[CST_RD + u];
    }
    if (t < D2) { sSc2[t] = cst[CST_SC2 + t]; sRc2[t] = cst[CST_RC2 + t]; }
    __syncthreads();

    int i = (blockIdx.x * 256 + t) >> 5;
    int l = t & 31;
    int nb = t >> 5;

    float eri = ER2[i];
    int dr = deg[i];
    int dcap = dr < CAP ? dr : CAP;
    const unsigned short* row = &esrc2[i * CAP];   // 64B-aligned contiguous row
    float aF0 = 0.0f, aF1 = 0.0f, aF2 = 0.0f, aF3 = 0.0f;
    float S0 = 0.0f, S1 = 0.0f, S2 = 0.0f, S3 = 0.0f;
    int j = 0;
    for (; j + 3 < dcap; j += 4) {
        ushort4 q = *(const ushort4*)&row[j];      // aligned: j multiple of 4
        int sA = q.x, sB = q.y, sC = q.z, sD = q.w;
        float wA = __expf(lrelu(EL2[sA] + eri));
        float wB = __expf(lrelu(EL2[sB] + eri));
        float wC = __expf(lrelu(EL2[sC] + eri));
        float wD = __expf(lrelu(EL2[sD] + eri));
        float vA = bu2f(F2[(size_t)sA * D2 + l]);
        float vB = bu2f(F2[(size_t)sB * D2 + l]);
        float vC = bu2f(F2[(size_t)sC * D2 + l]);
        float vD = bu2f(F2[(size_t)sD * D2 + l]);
        S0 += wA; S1 += wB; S2 += wC; S3 += wD;
        aF0 = fmaf(wA, vA, aF0);
        aF1 = fmaf(wB, vB, aF1);
        aF2 = fmaf(wC, vC, aF2);
        aF3 = fmaf(wD, vD, aF3);
    }
    for (; j < dcap; ++j) {
        int sA = (int)row[j];
        float wA = __expf(lrelu(EL2[sA] + eri));
        S0 += wA;
        aF0 = fmaf(wA, bu2f(F2[(size_t)sA * D2 + l]), aF0);
    }
    if (dr > CAP) {                                 // rare overflow edges
        int novf = *ovfc;
        for (int p = 0; p < novf; ++p) {
            int2 o = ovf[p];
            if (o.x == i) {
                float wA = __expf(lrelu(EL2[o.y] + eri));
                S0 += wA;
                aF0 = fmaf(wA, bu2f(F2[(size_t)o.y * D2 + l]), aF0);
            }
        }
    }
    float S = (S0 + S1) + (S2 + S3);
    float aF = (aF0 + aF1) + (aF2 + aF3);
    float inv = S > 0.0f ? 1.0f / S : 0.0f;

    float h2 = fmaxf((aF * inv + RS2[(size_t)i * D2 + l]) * sSc2[l] + sRc2[l], 0.0f);
    RS2[(size_t)i * D2 + l] = h2;

    // --- decoder, d-outer loop
    sH2[nb * D2 + l] = h2;
    float ac0 = 0.0f, ac1 = 0.0f, ac2 = 0.0f, ac3 = 0.0f;
#pragma unroll
    for (int d = 0; d < D2; ++d) {
        float h = sH2[nb * D2 + d];               // broadcast
        const float* wr = &sWd1[d * C1 + l];
        ac0 = fmaf(h, wr[0],  ac0);
        ac1 = fmaf(h, wr[32], ac1);
        ac2 = fmaf(h, wr[64], ac2);
        ac3 = fmaf(h, wr[96], ac3);
    }
    float rec = fmaxf(ac0 * sSd[l]      + sRd[l],      0.0f) * sWd2[l]
              + fmaxf(ac1 * sSd[l + 32] + sRd[l + 32], 0.0f) * sWd2[l + 32]
              + fmaxf(ac2 * sSd[l + 64] + sRd[l + 64], 0.0f) * sWd2[l + 64]
              + fmaxf(ac3 * sSd[l + 96] + sRd[l + 96], 0.0f) * sWd2[l + 96];
#pragma unroll
    for (int m = 16; m >= 1; m >>= 1) rec += __shfl_xor(rec, m);
    if (l == 0) out[NG * D2 + i] = rec + ldw(bd2, 0, bf);
}

// ---------------- graph mean pool: one block per graph, zero atomics ----------------
__global__ __launch_bounds__(256) void k_pool2(const int* __restrict__ gid,
                                               const float* __restrict__ H2,
                                               float* __restrict__ out) {
    __shared__ int sLo, sHi;
    __shared__ float sAcc[8 * D2];
    int g = blockIdx.x;
    int t = threadIdx.x;
    if (t == 0) {
        int lo = 0, hi = NN;
        while (lo < hi) { int m = (lo + hi) >> 1; if (gid[m] < g) lo = m + 1; else hi = m; }
        sLo = lo;
        lo = 0; hi = NN;
        while (lo < hi) { int m = (lo + hi) >> 1; if (gid[m] < g + 1) lo = m + 1; else hi = m; }
        sHi = lo;
    }
    __syncthreads();
    int lo = sLo, hi = sHi;
    int l = t & 31, row = t >> 5;
    float acc = 0.0f;
    for (int i = lo + row; i < hi; i += 8)
        acc += H2[(size_t)i * D2 + l];
    sAcc[row * D2 + l] = acc;
    __syncthreads();
    if (row == 0) {
#pragma unroll
        for (int r = 1; r < 8; ++r) acc += sAcc[r * D2 + l];
        float c = (float)(hi - lo);
        out[g * D2 + l] = acc / fmaxf(c, 1.0f);
    }
}

extern "C" void kernel_launch(void* const* d_in, const int* in_sizes, int n_in,
                              void* d_out, int out_size, void* d_ws, size_t ws_size,
                              hipStream_t stream) {
    const void* feat = d_in[0];
    const void* W1 = d_in[1];  const void* al1 = d_in[2];  const void* ar1 = d_in[3];
    const void* res1 = d_in[4]; const void* b1 = d_in[5];
    const void* g1g = d_in[6]; const void* g1b = d_in[7];
    const void* g1m = d_in[8]; const void* g1v = d_in[9];
    const void* W2 = d_in[10]; const void* al2 = d_in[11]; const void* ar2 = d_in[12];
    const void* res2 = d_in[13]; const void* b2v = d_in[14];
    const void* g2g = d_in[15]; const void* g2b = d_in[16];
    const void* g2m = d_in[17]; const void* g2v = d_in[18];
    const void* Wd1 = d_in[19]; const void* bd1 = d_in[20];
    const void* gdg = d_in[21]; const void* gdb = d_in[22];
    const void* gdm = d_in[23]; const void* gdv = d_in[24];
    const void* Wd2 = d_in[25]; const void* bd2 = d_in[26];
    const int* src = (const int*)d_in[27];
    const int* dst = (const int*)d_in[28];
    const int* gid = (const int*)d_in[29];

    unsigned int* wsu = (unsigned int*)d_ws;
    int* deg    = (int*)(wsu + UO_DEG);
    int* ovfc   = (int*)(wsu + UO_OVFC);
    int* flag   = (int*)(wsu + UO_FLAG);
    float* cst  = (float*)(wsu + UO_CST);
    unsigned short* esrc2 = (unsigned short*)(wsu + UO_ESRC2);
    int2* ovf   = (int2*)(wsu + UO_OVF);
    float* fcan = (float*)(wsu + UO_FCAN);
    unsigned short* F2 = (unsigned short*)(wsu + UO_F2);
    float* RS2  = (float*)(wsu + UO_RS2);
    float* EL2  = (float*)(wsu + UO_EL2);
    float* ER2  = (float*)(wsu + UO_ER2);

    hipMemsetAsync(d_ws, 0, (size_t)ZERO_UNITS * 4, stream);

    k_prep<<<(NE + 255) / 256, 256, 0, stream>>>(feat, dst, src, fcan, deg,
                                                 esrc2, ovf, ovfc,
                                                 W1, al1, ar1, res1, b1,
                                                 g1g, g1b, g1m, g1v,
                                                 b2v, g2g, g2b, g2m, g2v,
                                                 bd1, gdg, gdb, gdm, gdv,
                                                 flag, cst);

    k_layer1<<<(NN + 31) / 32, 256, 0, stream>>>(fcan, W2, res2, al2, ar2, flag, cst,
                                                 deg, esrc2, ovf, ovfc,
                                                 F2, RS2, EL2, ER2);

    k_final<<<(NN * 32) / 256, 256, 0, stream>>>(Wd1, Wd2, bd2, flag, cst,
                                                 deg, esrc2, ovf, ovfc,
                                                 F2, RS2, EL2, ER2,
                                                 (float*)d_out);

    k_pool2<<<NG, 256, 0, stream>>>(gid, RS2, (float*)d_out);
}

// Round 19
// 259.472 us; speedup vs baseline: 1.1362x; 1.0636x over previous
//
#include <hip/hip_runtime.h>
#include <hip/hip_bf16.h>

#define NN 50000
#define NE 800000
#define NG 64
#define C1 128    // H1*D1
#define D2 32
#define CAP 32    // capped slots per node; overflow handled exactly via ovf buffer
#define BN_EPS 1e-5f

// ---- constant-block layout (float offsets inside cst) ----
#define CST_A   0
#define CST_B   2
#define CST_P   4
#define CST_Q   132
#define CST_R   260
#define CST_SC2 388
#define CST_RC2 420
#define CST_SD  452
#define CST_RD  580
#define CST_N   1024

// ---- workspace layout (4-byte-unit offsets inside d_ws), ~20 MiB (ws is 256 MB) ----
#define UO_DEG   0                        // int[NN]  (zeroed)
#define UO_OVFC  50000                    // int[1]   (zeroed) overflow counter
#define ZERO_UNITS 50004
#define UO_FLAG  50004                    // int[1]
#define UO_CST   50008                    // float[CST_N]
#define UO_ESRC2 51040                    // ushort[CAP*NN] padded edge table (64B-aligned rows)
#define UO_OVF   851040                   // int2[NE] overflow (dst,src) — unconditional correctness
#define UO_FCAN  2451040                  // float[NN]
#define UO_F2    2501040                  // ushort[D2*NN] bf16 (16B aligned)
#define UO_RS2   3301040                  // float[D2*NN]; overwritten with h2 by k_final
#define UO_EL2   4901040                  // float[NN]
#define UO_ER2   4951040                  // float[NN]
#define UO_END   5001040

__device__ __forceinline__ float lrelu(float x) { return fmaxf(x, 0.2f * x); }
__device__ __forceinline__ float bu2f(unsigned int u) {
    union { unsigned int i; float f; } v; v.i = (u & 0xFFFFu) << 16; return v.f;
}
__device__ __forceinline__ unsigned short f2bu(float f) {
    union { float f; unsigned int i; } v; v.f = f;
    unsigned int r = v.i + 0x7FFFu + ((v.i >> 16) & 1u);
    return (unsigned short)(r >> 16);
}
__device__ __forceinline__ float pk_lo(unsigned int w) {
    union { unsigned int i; float f; } v; v.i = w << 16; return v.f;
}
__device__ __forceinline__ float pk_hi(unsigned int w) {
    union { unsigned int i; float f; } v; v.i = w & 0xFFFF0000u; return v.f;
}
__device__ __forceinline__ float ldw(const void* p, int i, int bf) {
    return bf ? bu2f(((const unsigned short*)p)[i]) : ((const float*)p)[i];
}
__device__ __forceinline__ int sniff64(const unsigned int* fw, int l) {
    int cnt = 0;
    for (int j = l; j < 256; j += 64) {
        unsigned int b = (fw[j] >> 8) & 0x7Fu;
        cnt += (b >= 0x3Au && b <= 0x41u) ? 1 : 0;
    }
#pragma unroll
    for (int m = 32; m >= 1; m >>= 1) cnt += __shfl_xor(cnt, m);
    return (cnt > 128) ? 1 : 0;
}

// ---------------- fcan + capped edge-table build + (block 0) const folding ----------------
__global__ void k_prep(const void* __restrict__ feat, const int* __restrict__ dst,
                       const int* __restrict__ src,
                       float* __restrict__ fcan, int* __restrict__ deg,
                       unsigned short* __restrict__ esrc2,
                       int2* __restrict__ ovf, int* __restrict__ ovfc,
                       const void* W1, const void* al1, const void* ar1,
                       const void* res1, const void* b1,
                       const void* g1g, const void* g1b, const void* g1m, const void* g1v,
                       const void* b2v, const void* g2g, const void* g2b,
                       const void* g2m, const void* g2v,
                       const void* bd1, const void* gdg, const void* gdb,
                       const void* gdm, const void* gdv,
                       int* __restrict__ flag, float* __restrict__ cst) {
    __shared__ int sBf;
    int t = threadIdx.x;
    if (t < 64) {
        int bf = sniff64((const unsigned int*)feat, t);
        if (t == 0) sBf = bf;
    }
    __syncthreads();
    int bf = sBf;

    if (blockIdx.x == 0) {             // fold tiny weights into fp32 constants
        if (t == 0) *flag = bf;
        if (t < 128) {
            if (t < 2) {
                float a = 0.0f, b = 0.0f;
                for (int d = 0; d < 64; ++d) {
                    float w = ldw(W1, t * 64 + d, bf);
                    a += w * ldw(al1, t * 64 + d, bf);
                    b += w * ldw(ar1, t * 64 + d, bf);
                }
                cst[CST_A + t] = a;
                cst[CST_B + t] = b;
            }
            {
                float sc = rsqrtf(ldw(g1v, t, bf) + BN_EPS) * ldw(g1g, t, bf);
                cst[CST_P + t] = ldw(W1, t, bf) * sc;
                cst[CST_Q + t] = ldw(res1, t, bf) * sc;
                cst[CST_R + t] = (ldw(b1, t, bf) - ldw(g1m, t, bf)) * sc + ldw(g1b, t, bf);
            }
            if (t < D2) {
                float sc = rsqrtf(ldw(g2v, t, bf) + BN_EPS) * ldw(g2g, t, bf);
                cst[CST_SC2 + t] = sc;
                cst[CST_RC2 + t] = (ldw(b2v, t, bf) - ldw(g2m, t, bf)) * sc + ldw(g2b, t, bf);
            }
            {
                float sc = rsqrtf(ldw(gdv, t, bf) + BN_EPS) * ldw(gdg, t, bf);
                cst[CST_SD + t] = sc;
                cst[CST_RD + t] = (ldw(bd1, t, bf) - ldw(gdm, t, bf)) * sc + ldw(gdb, t, bf);
            }
        }
    }

    int k = blockIdx.x * blockDim.x + t;
    if (k < NN) fcan[k] = ldw(feat, k, bf);
    if (k < NE) {
        int d = dst[k];
        int slot = atomicAdd(&deg[d], 1);
        if (slot < CAP) {
            esrc2[d * CAP + slot] = (unsigned short)src[k];
        } else {
            int p = atomicAdd(ovfc, 1);           // rare (~tens of edges)
            ovf[p] = make_int2(d, src[k]);
        }
    }
}

// ---------------- layer-1: 32 nodes/block; single-chunk gather + packed projection ----------------
__global__ __launch_bounds__(256) void k_layer1(
        const float* __restrict__ fcan, const void* W2, const void* res2,
        const void* al2, const void* ar2,
        const int* __restrict__ flag, const float* __restrict__ cst,
        const int* __restrict__ deg, const unsigned short* __restrict__ esrc2,
        const int2* __restrict__ ovf, const int* __restrict__ ovfc,
        unsigned short* __restrict__ F2, float* __restrict__ RS2,
        float* __restrict__ EL2, float* __restrict__ ER2) {
    __shared__ unsigned int sW2pk[32 * 66];  // [l][cw], (c,c+64) bf16 pairs
    __shared__ unsigned int sR2pk[32 * 66];
    __shared__ unsigned int sH1pk[32 * 66];
    __shared__ float sP[C1], sQ[C1], sR[C1];
    __shared__ float sAl[D2], sAr[D2];
    int t = threadIdx.x;
    int bf = *flag;
    for (int u = t; u < 2048; u += 256) {
        int cw = u >> 5, l2 = u & 31;
        unsigned int wlo = (unsigned int)f2bu(ldw(W2, cw * D2 + l2, bf));
        unsigned int whi = (unsigned int)f2bu(ldw(W2, (cw + 64) * D2 + l2, bf));
        sW2pk[l2 * 66 + cw] = wlo | (whi << 16);
        unsigned int rlo = (unsigned int)f2bu(ldw(res2, cw * D2 + l2, bf));
        unsigned int rhi = (unsigned int)f2bu(ldw(res2, (cw + 64) * D2 + l2, bf));
        sR2pk[l2 * 66 + cw] = rlo | (rhi << 16);
    }
    if (t < C1) { sP[t] = cst[CST_P + t]; sQ[t] = cst[CST_Q + t]; sR[t] = cst[CST_R + t]; }
    if (t < D2) { sAl[t] = ldw(al2, t, bf); sAr[t] = ldw(ar2, t, bf); }
    __syncthreads();

    int l = t & 31;
    int g = t >> 5;
    int base = blockIdx.x * 32;
    float A0 = cst[CST_A + 0], A1 = cst[CST_A + 1];
    float B0 = cst[CST_B + 0], B1 = cst[CST_B + 1];

    int dcap[4], draw[4];
    float fiK[4];
#pragma unroll
    for (int k = 0; k < 4; ++k) {
        int i = base + g * 4 + k;
        if (i < NN) {
            draw[k] = deg[i];
            dcap[k] = draw[k] < CAP ? draw[k] : CAP;
            fiK[k] = fcan[i];
        } else { draw[k] = 0; dcap[k] = 0; fiK[k] = 0.0f; }
    }
    float S0[4], S1[4], N0[4], N1[4];
#pragma unroll
    for (int k = 0; k < 4; ++k) { S0[k] = S1[k] = N0[k] = N1[k] = 0.0f; }
    int sA[4];
#pragma unroll
    for (int k = 0; k < 4; ++k)
        sA[k] = (l < dcap[k]) ? (int)esrc2[(base + g * 4 + k) * CAP + l] : 0;
    float fA[4];
#pragma unroll
    for (int k = 0; k < 4; ++k) fA[k] = fcan[sA[k]];
#pragma unroll
    for (int k = 0; k < 4; ++k) {
        if (l < dcap[k]) {
            float w0 = __expf(lrelu(A0 * fA[k] + B0 * fiK[k]));
            float w1 = __expf(lrelu(A1 * fA[k] + B1 * fiK[k]));
            S0[k] += w0; N0[k] += w0 * fA[k];
            S1[k] += w1; N1[k] += w1 * fA[k];
        }
    }
    // rare overflow edges (deg > CAP)
#pragma unroll
    for (int k = 0; k < 4; ++k) {
        if (draw[k] > CAP) {
            int i = base + g * 4 + k;
            int novf = *ovfc;
            for (int p = l; p < novf; p += 32) {
                int2 o = ovf[p];
                if (o.x == i) {
                    float fs = fcan[o.y];
                    float w0 = __expf(lrelu(A0 * fs + B0 * fiK[k]));
                    float w1 = __expf(lrelu(A1 * fs + B1 * fiK[k]));
                    S0[k] += w0; N0[k] += w0 * fs;
                    S1[k] += w1; N1[k] += w1 * fs;
                }
            }
        }
    }
#pragma unroll
    for (int m = 16; m >= 1; m >>= 1) {
#pragma unroll
        for (int k = 0; k < 4; ++k) {
            S0[k] += __shfl_xor(S0[k], m); N0[k] += __shfl_xor(N0[k], m);
            S1[k] += __shfl_xor(S1[k], m); N1[k] += __shfl_xor(N1[k], m);
        }
    }
#pragma unroll
    for (int k = 0; k < 4; ++k) {
        int slot = g * 4 + k;
        float T0 = S0[k] > 0.0f ? N0[k] / S0[k] : 0.0f;
        float T1 = S1[k] > 0.0f ? N1[k] / S1[k] : 0.0f;
        float h0  = fmaxf(sP[l]      * T0 + sQ[l]      * fiK[k] + sR[l],      0.0f);
        float h1v = fmaxf(sP[l + 32] * T0 + sQ[l + 32] * fiK[k] + sR[l + 32], 0.0f);
        float h2v = fmaxf(sP[l + 64] * T1 + sQ[l + 64] * fiK[k] + sR[l + 64], 0.0f);
        float h3v = fmaxf(sP[l + 96] * T1 + sQ[l + 96] * fiK[k] + sR[l + 96], 0.0f);
        sH1pk[slot * 66 + l]      = (unsigned int)f2bu(h0)  | ((unsigned int)f2bu(h2v) << 16);
        sH1pk[slot * 66 + l + 32] = (unsigned int)f2bu(h1v) | ((unsigned int)f2bu(h3v) << 16);
    }
    __syncthreads();

    int w = t >> 6;
    int half = (t >> 5) & 1;
    int nb0 = w * 8 + half * 4;
    float aF[4] = {0.f, 0.f, 0.f, 0.f}, aR[4] = {0.f, 0.f, 0.f, 0.f};
    for (int cw = 0; cw < 64; cw += 2) {
        uint2 wq = *(const uint2*)&sW2pk[l * 66 + cw];
        uint2 rq = *(const uint2*)&sR2pk[l * 66 + cw];
        float w_a = pk_lo(wq.x), w_b = pk_hi(wq.x), w_c = pk_lo(wq.y), w_d = pk_hi(wq.y);
        float r_a = pk_lo(rq.x), r_b = pk_hi(rq.x), r_c = pk_lo(rq.y), r_d = pk_hi(rq.y);
#pragma unroll
        for (int n = 0; n < 4; ++n) {
            uint2 hq = *(const uint2*)&sH1pk[(nb0 + n) * 66 + cw];
            float h_a = pk_lo(hq.x), h_b = pk_hi(hq.x), h_c = pk_lo(hq.y), h_d = pk_hi(hq.y);
            aF[n] = fmaf(h_a, w_a, fmaf(h_b, w_b, fmaf(h_c, w_c, fmaf(h_d, w_d, aF[n]))));
            aR[n] = fmaf(h_a, r_a, fmaf(h_b, r_b, fmaf(h_c, r_c, fmaf(h_d, r_d, aR[n]))));
        }
    }
#pragma unroll
    for (int n = 0; n < 4; ++n) {
        int i = base + nb0 + n;
        if (i < NN) {
            float elp = aF[n] * sAl[l], erp = aF[n] * sAr[l];
#pragma unroll
            for (int m = 16; m >= 1; m >>= 1) {
                elp += __shfl_xor(elp, m);
                erp += __shfl_xor(erp, m);
            }
            if (l == 0) { EL2[i] = elp; ER2[i] = erp; }
            F2[(size_t)i * D2 + l]  = f2bu(aF[n]);
            RS2[(size_t)i * D2 + l] = aR[n];
        }
    }
}

// ---------------- layer-2 gather (8 independent chains via uint4 row loads) + decoder ----------------
__global__ __launch_bounds__(256) void k_final(
        const void* Wd1, const void* Wd2, const void* bd2,
        const int* __restrict__ flag, const float* __restrict__ cst,
        const int* __restrict__ deg, const unsigned short* __restrict__ esrc2,
        const int2* __restrict__ ovf, const int* __restrict__ ovfc,
        const unsigned short* __restrict__ F2, float* __restrict__ RS2,
        const float* __restrict__ EL2, const float* __restrict__ ER2,
        float* __restrict__ out) {
    __shared__ float sWd1[C1 * D2];
    __shared__ float sWd2[C1];
    __shared__ float sSd[C1], sRd[C1];
    __shared__ float sSc2[D2], sRc2[D2];
    __shared__ float sH2[8 * D2];
    int t = threadIdx.x;
    int bf = *flag;
    for (int u = t; u < C1 * D2; u += 256) sWd1[u] = ldw(Wd1, u, bf);
    for (int u = t; u < C1; u += 256) {
        sWd2[u] = ldw(Wd2, u, bf);
        sSd[u] = cst[CST_SD + u]; sRd[u] = cst[CST_RD + u];
    }
    if (t < D2) { sSc2[t] = cst[CST_SC2 + t]; sRc2[t] = cst[CST_RC2 + t]; }
    __syncthreads();

    int i = (blockIdx.x * 256 + t) >> 5;
    int l = t & 31;
    int nb = t >> 5;

    float eri = ER2[i];
    int dr = deg[i];
    int dcap = dr < CAP ? dr : CAP;
    const unsigned short* row = &esrc2[i * CAP];   // 64B-aligned contiguous row
    float aF0 = 0.f, aF1 = 0.f, aF2 = 0.f, aF3 = 0.f, aF4 = 0.f, aF5 = 0.f, aF6 = 0.f, aF7 = 0.f;
    float S0 = 0.f, S1 = 0.f, S2 = 0.f, S3 = 0.f, S4 = 0.f, S5 = 0.f, S6 = 0.f, S7 = 0.f;
    int j = 0;
    for (; j + 7 < dcap; j += 8) {                 // 8 independent chains per step
        uint4 qq = *(const uint4*)&row[j];         // 8 edge ids, one 16B load
        int s0 = qq.x & 0xFFFF, s1 = qq.x >> 16;
        int s2 = qq.y & 0xFFFF, s3 = qq.y >> 16;
        int s4 = qq.z & 0xFFFF, s5 = qq.z >> 16;
        int s6 = qq.w & 0xFFFF, s7 = qq.w >> 16;
        float w0 = __expf(lrelu(EL2[s0] + eri));
        float w1 = __expf(lrelu(EL2[s1] + eri));
        float w2 = __expf(lrelu(EL2[s2] + eri));
        float w3 = __expf(lrelu(EL2[s3] + eri));
        float w4 = __expf(lrelu(EL2[s4] + eri));
        float w5 = __expf(lrelu(EL2[s5] + eri));
        float w6 = __expf(lrelu(EL2[s6] + eri));
        float w7 = __expf(lrelu(EL2[s7] + eri));
        float v0 = bu2f(F2[(size_t)s0 * D2 + l]);
        float v1 = bu2f(F2[(size_t)s1 * D2 + l]);
        float v2 = bu2f(F2[(size_t)s2 * D2 + l]);
        float v3 = bu2f(F2[(size_t)s3 * D2 + l]);
        float v4 = bu2f(F2[(size_t)s4 * D2 + l]);
        float v5 = bu2f(F2[(size_t)s5 * D2 + l]);
        float v6 = bu2f(F2[(size_t)s6 * D2 + l]);
        float v7 = bu2f(F2[(size_t)s7 * D2 + l]);
        S0 += w0; S1 += w1; S2 += w2; S3 += w3;
        S4 += w4; S5 += w5; S6 += w6; S7 += w7;
        aF0 = fmaf(w0, v0, aF0); aF1 = fmaf(w1, v1, aF1);
        aF2 = fmaf(w2, v2, aF2); aF3 = fmaf(w3, v3, aF3);
        aF4 = fmaf(w4, v4, aF4); aF5 = fmaf(w5, v5, aF5);
        aF6 = fmaf(w6, v6, aF6); aF7 = fmaf(w7, v7, aF7);
    }
    for (; j + 3 < dcap; j += 4) {                 // 4-chain step
        ushort4 q = *(const ushort4*)&row[j];
        int sA = q.x, sB = q.y, sC = q.z, sD = q.w;
        float wA = __expf(lrelu(EL2[sA] + eri));
        float wB = __expf(lrelu(EL2[sB] + eri));
        float wC = __expf(lrelu(EL2[sC] + eri));
        float wD = __expf(lrelu(EL2[sD] + eri));
        float vA = bu2f(F2[(size_t)sA * D2 + l]);
        float vB = bu2f(F2[(size_t)sB * D2 + l]);
        float vC = bu2f(F2[(size_t)sC * D2 + l]);
        float vD = bu2f(F2[(size_t)sD * D2 + l]);
        S0 += wA; S1 += wB; S2 += wC; S3 += wD;
        aF0 = fmaf(wA, vA, aF0); aF1 = fmaf(wB, vB, aF1);
        aF2 = fmaf(wC, vC, aF2); aF3 = fmaf(wD, vD, aF3);
    }
    for (; j < dcap; ++j) {
        int sA = (int)row[j];
        float wA = __expf(lrelu(EL2[sA] + eri));
        S0 += wA;
        aF0 = fmaf(wA, bu2f(F2[(size_t)sA * D2 + l]), aF0);
    }
    if (dr > CAP) {                                 // rare overflow edges
        int novf = *ovfc;
        for (int p = 0; p < novf; ++p) {
            int2 o = ovf[p];
            if (o.x == i) {
                float wA = __expf(lrelu(EL2[o.y] + eri));
                S0 += wA;
                aF0 = fmaf(wA, bu2f(F2[(size_t)o.y * D2 + l]), aF0);
            }
        }
    }
    float S = ((S0 + S1) + (S2 + S3)) + ((S4 + S5) + (S6 + S7));
    float aF = ((aF0 + aF1) + (aF2 + aF3)) + ((aF4 + aF5) + (aF6 + aF7));
    float inv = S > 0.0f ? 1.0f / S : 0.0f;

    float h2 = fmaxf((aF * inv + RS2[(size_t)i * D2 + l]) * sSc2[l] + sRc2[l], 0.0f);
    RS2[(size_t)i * D2 + l] = h2;

    // --- decoder, d-outer loop
    sH2[nb * D2 + l] = h2;
    float ac0 = 0.0f, ac1 = 0.0f, ac2 = 0.0f, ac3 = 0.0f;
#pragma unroll
    for (int d = 0; d < D2; ++d) {
        float h = sH2[nb * D2 + d];               // broadcast
        const float* wr = &sWd1[d * C1 + l];
        ac0 = fmaf(h, wr[0],  ac0);
        ac1 = fmaf(h, wr[32], ac1);
        ac2 = fmaf(h, wr[64], ac2);
        ac3 = fmaf(h, wr[96], ac3);
    }
    float rec = fmaxf(ac0 * sSd[l]      + sRd[l],      0.0f) * sWd2[l]
              + fmaxf(ac1 * sSd[l + 32] + sRd[l + 32], 0.0f) * sWd2[l + 32]
              + fmaxf(ac2 * sSd[l + 64] + sRd[l + 64], 0.0f) * sWd2[l + 64]
              + fmaxf(ac3 * sSd[l + 96] + sRd[l + 96], 0.0f) * sWd2[l + 96];
#pragma unroll
    for (int m = 16; m >= 1; m >>= 1) rec += __shfl_xor(rec, m);
    if (l == 0) out[NG * D2 + i] = rec + ldw(bd2, 0, bf);
}

// ---------------- graph mean pool: 32 rows x float4 (4x memory-level parallelism) ----------------
__global__ __launch_bounds__(256) void k_pool2(const int* __restrict__ gid,
                                               const float* __restrict__ H2,
                                               float* __restrict__ out) {
    __shared__ int sLo, sHi;
    __shared__ float sAcc[32 * 32];   // [row][dim]
    int g = blockIdx.x;
    int t = threadIdx.x;
    if (t == 0) {
        int lo = 0, hi = NN;
        while (lo < hi) { int m = (lo + hi) >> 1; if (gid[m] < g) lo = m + 1; else hi = m; }
        sLo = lo;
        lo = 0; hi = NN;
        while (lo < hi) { int m = (lo + hi) >> 1; if (gid[m] < g + 1) lo = m + 1; else hi = m; }
        sHi = lo;
    }
    __syncthreads();
    int lo = sLo, hi = sHi;
    int q = t & 7;         // quad: dims [4q, 4q+4)
    int row = t >> 3;      // 32 rows of nodes in flight
    float4 acc = make_float4(0.f, 0.f, 0.f, 0.f);
    for (int i = lo + row; i < hi; i += 32) {
        float4 v = ((const float4*)&H2[(size_t)i * D2])[q];
        acc.x += v.x; acc.y += v.y; acc.z += v.z; acc.w += v.w;
    }
    *(float4*)&sAcc[row * 32 + 4 * q] = acc;
    __syncthreads();
    if (t < 32) {          // dim t: sum 32 rows (conflict-free: bank = t)
        float a = 0.0f;
        for (int r = 0; r < 32; ++r) a += sAcc[r * 32 + t];
        float c = (float)(hi - lo);
        out[g * D2 + t] = a / fmaxf(c, 1.0f);
    }
}

extern "C" void kernel_launch(void* const* d_in, const int* in_sizes, int n_in,
                              void* d_out, int out_size, void* d_ws, size_t ws_size,
                              hipStream_t stream) {
    const void* feat = d_in[0];
    const void* W1 = d_in[1];  const void* al1 = d_in[2];  const void* ar1 = d_in[3];
    const void* res1 = d_in[4]; const void* b1 = d_in[5];
    const void* g1g = d_in[6]; const void* g1b = d_in[7];
    const void* g1m = d_in[8]; const void* g1v = d_in[9];
    const void* W2 = d_in[10]; const void* al2 = d_in[11]; const void* ar2 = d_in[12];
    const void* res2 = d_in[13]; const void* b2v = d_in[14];
    const void* g2g = d_in[15]; const void* g2b = d_in[16];
    const void* g2m = d_in[17]; const void* g2v = d_in[18];
    const void* Wd1 = d_in[19]; const void* bd1 = d_in[20];
    const void* gdg = d_in[21]; const void* gdb = d_in[22];
    const void* gdm = d_in[23]; const void* gdv = d_in[24];
    const void* Wd2 = d_in[25]; const void* bd2 = d_in[26];
    const int* src = (const int*)d_in[27];
    const int* dst = (const int*)d_in[28];
    const int* gid = (const int*)d_in[29];

    unsigned int* wsu = (unsigned int*)d_ws;
    int* deg    = (int*)(wsu + UO_DEG);
    int* ovfc   = (int*)(wsu + UO_OVFC);
    int* flag   = (int*)(wsu + UO_FLAG);
    float* cst  = (float*)(wsu + UO_CST);
    unsigned short* esrc2 = (unsigned short*)(wsu + UO_ESRC2);
    int2* ovf   = (int2*)(wsu + UO_OVF);
    float* fcan = (float*)(wsu + UO_FCAN);
    unsigned short* F2 = (unsigned short*)(wsu + UO_F2);
    float* RS2  = (float*)(wsu + UO_RS2);
    float* EL2  = (float*)(wsu + UO_EL2);
    float* ER2  = (float*)(wsu + UO_ER2);

    hipMemsetAsync(d_ws, 0, (size_t)ZERO_UNITS * 4, stream);

    k_prep<<<(NE + 255) / 256, 256, 0, stream>>>(feat, dst, src, fcan, deg,
                                                 esrc2, ovf, ovfc,
                                                 W1, al1, ar1, res1, b1,
                                                 g1g, g1b, g1m, g1v,
                                                 b2v, g2g, g2b, g2m, g2v,
                                                 bd1, gdg, gdb, gdm, gdv,
                                                 flag, cst);

    k_layer1<<<(NN + 31) / 32, 256, 0, stream>>>(fcan, W2, res2, al2, ar2, flag, cst,
                                                 deg, esrc2, ovf, ovfc,
                                                 F2, RS2, EL2, ER2);

    k_final<<<(NN * 32) / 256, 256, 0, stream>>>(Wd1, Wd2, bd2, flag, cst,
                                                 deg, esrc2, ovf, ovfc,
                                                 F2, RS2, EL2, ER2,
                                                 (float*)d_out);

    k_pool2<<<NG, 256, 0, stream>>>(gid, RS2, (float*)d_out);
}

// Round 20
// 257.050 us; speedup vs baseline: 1.1469x; 1.0094x over previous
//
#include <hip/hip_runtime.h>
#include <hip/hip_bf16.h>

#define NN 50000
#define NE 800000
#define NG 64
#define C1 128    // H1*D1
#define D2 32
#define CAP 32    // capped slots per node; overflow handled exactly via ovf buffer
#define RNG 6250  // NN/8: dst-range width per XCD partition
#define NCH 391   // ceil(NE/2048) edge chunks
#define BN_EPS 1e-5f

// ---- constant-block layout (float offsets inside cst) ----
#define CST_A   0
#define CST_B   2
#define CST_P   4
#define CST_Q   132
#define CST_R   260
#define CST_SC2 388
#define CST_RC2 420
#define CST_SD  452
#define CST_RD  580
#define CST_N   1024

// ---- workspace layout (4-byte-unit offsets inside d_ws), ~23 MiB (ws is 256 MB) ----
#define UO_DEGP  0                        // int[16*NN] padded: one counter per 64B line (zeroed)
#define UO_OVFC  800000                   // int[1]   (zeroed)
#define ZERO_UNITS 800004
#define UO_FLAG  800004                   // int[1]
#define UO_CST   800008                   // float[CST_N]
#define UO_ESRC2 801040                   // ushort[CAP*NN] padded edge table (64B-aligned rows)
#define UO_OVF   1601040                  // int2[NE] overflow (dst,src)
#define UO_FCAN  3201040                  // float[NN]
#define UO_F2    3251040                  // ushort[D2*NN] bf16 (16B aligned)
#define UO_RS2   4051040                  // float[D2*NN]; overwritten with h2 by k_final
#define UO_EL2   5651040                  // float[NN]
#define UO_ER2   5701040                  // float[NN]
#define UO_END   5751040

__device__ __forceinline__ float lrelu(float x) { return fmaxf(x, 0.2f * x); }
__device__ __forceinline__ float bu2f(unsigned int u) {
    union { unsigned int i; float f; } v; v.i = (u & 0xFFFFu) << 16; return v.f;
}
__device__ __forceinline__ unsigned short f2bu(float f) {
    union { float f; unsigned int i; } v; v.f = f;
    unsigned int r = v.i + 0x7FFFu + ((v.i >> 16) & 1u);
    return (unsigned short)(r >> 16);
}
__device__ __forceinline__ float pk_lo(unsigned int w) {
    union { unsigned int i; float f; } v; v.i = w << 16; return v.f;
}
__device__ __forceinline__ float pk_hi(unsigned int w) {
    union { unsigned int i; float f; } v; v.i = w & 0xFFFF0000u; return v.f;
}
__device__ __forceinline__ float ldw(const void* p, int i, int bf) {
    return bf ? bu2f(((const unsigned short*)p)[i]) : ((const float*)p)[i];
}
__device__ __forceinline__ int sniff64(const unsigned int* fw, int l) {
    int cnt = 0;
    for (int j = l; j < 256; j += 64) {
        unsigned int b = (fw[j] >> 8) & 0x7Fu;
        cnt += (b >= 0x3Au && b <= 0x41u) ? 1 : 0;
    }
#pragma unroll
    for (int m = 32; m >= 1; m >>= 1) cnt += __shfl_xor(cnt, m);
    return (cnt > 128) ? 1 : 0;
}

// ---------------- edge-table build, XCD-range partitioned + fcan + const folding ----------------
// grid = NCH*8; block b: edge chunk b>>3, dst range (b&7)*RNG..+RNG. With round-robin
// block->XCD dispatch each XCD dirties only its 1/8 of esrc2/degp (kills 8x L2 writeback dup).
__global__ void k_prep(const void* __restrict__ feat, const int* __restrict__ dst,
                       const int* __restrict__ src,
                       float* __restrict__ fcan, int* __restrict__ degp,
                       unsigned short* __restrict__ esrc2,
                       int2* __restrict__ ovf, int* __restrict__ ovfc,
                       const void* W1, const void* al1, const void* ar1,
                       const void* res1, const void* b1,
                       const void* g1g, const void* g1b, const void* g1m, const void* g1v,
                       const void* b2v, const void* g2g, const void* g2b,
                       const void* g2m, const void* g2v,
                       const void* bd1, const void* gdg, const void* gdb,
                       const void* gdm, const void* gdv,
                       int* __restrict__ flag, float* __restrict__ cst) {
    __shared__ int sBf;
    int t = threadIdx.x;
    if (t < 64) {
        int bf = sniff64((const unsigned int*)feat, t);
        if (t == 0) sBf = bf;
    }
    __syncthreads();
    int bf = sBf;
    int r = blockIdx.x & 7;
    int c = blockIdx.x >> 3;

    if (blockIdx.x == 0) {             // fold tiny weights into fp32 constants
        if (t == 0) *flag = bf;
        if (t < 128) {
            if (t < 2) {
                float a = 0.0f, b = 0.0f;
                for (int d = 0; d < 64; ++d) {
                    float w = ldw(W1, t * 64 + d, bf);
                    a += w * ldw(al1, t * 64 + d, bf);
                    b += w * ldw(ar1, t * 64 + d, bf);
                }
                cst[CST_A + t] = a;
                cst[CST_B + t] = b;
            }
            {
                float sc = rsqrtf(ldw(g1v, t, bf) + BN_EPS) * ldw(g1g, t, bf);
                cst[CST_P + t] = ldw(W1, t, bf) * sc;
                cst[CST_Q + t] = ldw(res1, t, bf) * sc;
                cst[CST_R + t] = (ldw(b1, t, bf) - ldw(g1m, t, bf)) * sc + ldw(g1b, t, bf);
            }
            if (t < D2) {
                float sc = rsqrtf(ldw(g2v, t, bf) + BN_EPS) * ldw(g2g, t, bf);
                cst[CST_SC2 + t] = sc;
                cst[CST_RC2 + t] = (ldw(b2v, t, bf) - ldw(g2m, t, bf)) * sc + ldw(g2b, t, bf);
            }
            {
                float sc = rsqrtf(ldw(gdv, t, bf) + BN_EPS) * ldw(gdg, t, bf);
                cst[CST_SD + t] = sc;
                cst[CST_RD + t] = (ldw(bd1, t, bf) - ldw(gdm, t, bf)) * sc + ldw(gdb, t, bf);
            }
        }
    }

    int lo = r * RNG, hi = lo + RNG;
#pragma unroll
    for (int j = 0; j < 8; ++j) {
        int k = c * 2048 + j * 256 + t;
        if (k < NE) {
            int d = dst[k];
            if (d >= lo && d < hi) {
                int slot = atomicAdd(&degp[d << 4], 1);
                if (slot < CAP) {
                    esrc2[d * CAP + slot] = (unsigned short)src[k];
                } else {
                    int p = atomicAdd(ovfc, 1);    // rare
                    ovf[p] = make_int2(d, src[k]);
                }
            }
        }
        if (r == 0 && k < NN) fcan[k] = ldw(feat, k, bf);
    }
}

// ---------------- layer-1: 32 nodes/block; single-chunk gather + packed projection ----------------
__global__ __launch_bounds__(256) void k_layer1(
        const float* __restrict__ fcan, const void* W2, const void* res2,
        const void* al2, const void* ar2,
        const int* __restrict__ flag, const float* __restrict__ cst,
        const int* __restrict__ degp, const unsigned short* __restrict__ esrc2,
        const int2* __restrict__ ovf, const int* __restrict__ ovfc,
        unsigned short* __restrict__ F2, float* __restrict__ RS2,
        float* __restrict__ EL2, float* __restrict__ ER2) {
    __shared__ unsigned int sW2pk[32 * 66];  // [l][cw], (c,c+64) bf16 pairs
    __shared__ unsigned int sR2pk[32 * 66];
    __shared__ unsigned int sH1pk[32 * 66];
    __shared__ float sP[C1], sQ[C1], sR[C1];
    __shared__ float sAl[D2], sAr[D2];
    int t = threadIdx.x;
    int bf = *flag;
    for (int u = t; u < 2048; u += 256) {
        int cw = u >> 5, l2 = u & 31;
        unsigned int wlo = (unsigned int)f2bu(ldw(W2, cw * D2 + l2, bf));
        unsigned int whi = (unsigned int)f2bu(ldw(W2, (cw + 64) * D2 + l2, bf));
        sW2pk[l2 * 66 + cw] = wlo | (whi << 16);
        unsigned int rlo = (unsigned int)f2bu(ldw(res2, cw * D2 + l2, bf));
        unsigned int rhi = (unsigned int)f2bu(ldw(res2, (cw + 64) * D2 + l2, bf));
        sR2pk[l2 * 66 + cw] = rlo | (rhi << 16);
    }
    if (t < C1) { sP[t] = cst[CST_P + t]; sQ[t] = cst[CST_Q + t]; sR[t] = cst[CST_R + t]; }
    if (t < D2) { sAl[t] = ldw(al2, t, bf); sAr[t] = ldw(ar2, t, bf); }
    __syncthreads();

    int l = t & 31;
    int g = t >> 5;
    int base = blockIdx.x * 32;
    float A0 = cst[CST_A + 0], A1 = cst[CST_A + 1];
    float B0 = cst[CST_B + 0], B1 = cst[CST_B + 1];

    int dcap[4], draw[4];
    float fiK[4];
#pragma unroll
    for (int k = 0; k < 4; ++k) {
        int i = base + g * 4 + k;
        if (i < NN) {
            draw[k] = degp[i << 4];
            dcap[k] = draw[k] < CAP ? draw[k] : CAP;
            fiK[k] = fcan[i];
        } else { draw[k] = 0; dcap[k] = 0; fiK[k] = 0.0f; }
    }
    float S0[4], S1[4], N0[4], N1[4];
#pragma unroll
    for (int k = 0; k < 4; ++k) { S0[k] = S1[k] = N0[k] = N1[k] = 0.0f; }
    int sA[4];
#pragma unroll
    for (int k = 0; k < 4; ++k)
        sA[k] = (l < dcap[k]) ? (int)esrc2[(base + g * 4 + k) * CAP + l] : 0;
    float fA[4];
#pragma unroll
    for (int k = 0; k < 4; ++k) fA[k] = fcan[sA[k]];
#pragma unroll
    for (int k = 0; k < 4; ++k) {
        if (l < dcap[k]) {
            float w0 = __expf(lrelu(A0 * fA[k] + B0 * fiK[k]));
            float w1 = __expf(lrelu(A1 * fA[k] + B1 * fiK[k]));
            S0[k] += w0; N0[k] += w0 * fA[k];
            S1[k] += w1; N1[k] += w1 * fA[k];
        }
    }
    // rare overflow edges (deg > CAP)
#pragma unroll
    for (int k = 0; k < 4; ++k) {
        if (draw[k] > CAP) {
            int i = base + g * 4 + k;
            int novf = *ovfc;
            for (int p = l; p < novf; p += 32) {
                int2 o = ovf[p];
                if (o.x == i) {
                    float fs = fcan[o.y];
                    float w0 = __expf(lrelu(A0 * fs + B0 * fiK[k]));
                    float w1 = __expf(lrelu(A1 * fs + B1 * fiK[k]));
                    S0[k] += w0; N0[k] += w0 * fs;
                    S1[k] += w1; N1[k] += w1 * fs;
                }
            }
        }
    }
#pragma unroll
    for (int m = 16; m >= 1; m >>= 1) {
#pragma unroll
        for (int k = 0; k < 4; ++k) {
            S0[k] += __shfl_xor(S0[k], m); N0[k] += __shfl_xor(N0[k], m);
            S1[k] += __shfl_xor(S1[k], m); N1[k] += __shfl_xor(N1[k], m);
        }
    }
#pragma unroll
    for (int k = 0; k < 4; ++k) {
        int slot = g * 4 + k;
        float T0 = S0[k] > 0.0f ? N0[k] / S0[k] : 0.0f;
        float T1 = S1[k] > 0.0f ? N1[k] / S1[k] : 0.0f;
        float h0  = fmaxf(sP[l]      * T0 + sQ[l]      * fiK[k] + sR[l],      0.0f);
        float h1v = fmaxf(sP[l + 32] * T0 + sQ[l + 32] * fiK[k] + sR[l + 32], 0.0f);
        float h2v = fmaxf(sP[l + 64] * T1 + sQ[l + 64] * fiK[k] + sR[l + 64], 0.0f);
        float h3v = fmaxf(sP[l + 96] * T1 + sQ[l + 96] * fiK[k] + sR[l + 96], 0.0f);
        sH1pk[slot * 66 + l]      = (unsigned int)f2bu(h0)  | ((unsigned int)f2bu(h2v) << 16);
        sH1pk[slot * 66 + l + 32] = (unsigned int)f2bu(h1v) | ((unsigned int)f2bu(h3v) << 16);
    }
    __syncthreads();

    int w = t >> 6;
    int half = (t >> 5) & 1;
    int nb0 = w * 8 + half * 4;
    float aF[4] = {0.f, 0.f, 0.f, 0.f}, aR[4] = {0.f, 0.f, 0.f, 0.f};
    for (int cw = 0; cw < 64; cw += 2) {
        uint2 wq = *(const uint2*)&sW2pk[l * 66 + cw];
        uint2 rq = *(const uint2*)&sR2pk[l * 66 + cw];
        float w_a = pk_lo(wq.x), w_b = pk_hi(wq.x), w_c = pk_lo(wq.y), w_d = pk_hi(wq.y);
        float r_a = pk_lo(rq.x), r_b = pk_hi(rq.x), r_c = pk_lo(rq.y), r_d = pk_hi(rq.y);
#pragma unroll
        for (int n = 0; n < 4; ++n) {
            uint2 hq = *(const uint2*)&sH1pk[(nb0 + n) * 66 + cw];
            float h_a = pk_lo(hq.x), h_b = pk_hi(hq.x), h_c = pk_lo(hq.y), h_d = pk_hi(hq.y);
            aF[n] = fmaf(h_a, w_a, fmaf(h_b, w_b, fmaf(h_c, w_c, fmaf(h_d, w_d, aF[n]))));
            aR[n] = fmaf(h_a, r_a, fmaf(h_b, r_b, fmaf(h_c, r_c, fmaf(h_d, r_d, aR[n]))));
        }
    }
#pragma unroll
    for (int n = 0; n < 4; ++n) {
        int i = base + nb0 + n;
        if (i < NN) {
            float elp = aF[n] * sAl[l], erp = aF[n] * sAr[l];
#pragma unroll
            for (int m = 16; m >= 1; m >>= 1) {
                elp += __shfl_xor(elp, m);
                erp += __shfl_xor(erp, m);
            }
            if (l == 0) { EL2[i] = elp; ER2[i] = erp; }
            F2[(size_t)i * D2 + l]  = f2bu(aF[n]);
            RS2[(size_t)i * D2 + l] = aR[n];
        }
    }
}

// ---------------- layer-2 gather (8 independent chains via uint4 row loads) + decoder ----------------
__global__ __launch_bounds__(256) void k_final(
        const void* Wd1, const void* Wd2, const void* bd2,
        const int* __restrict__ flag, const float* __restrict__ cst,
        const int* __restrict__ degp, const unsigned short* __restrict__ esrc2,
        const int2* __restrict__ ovf, const int* __restrict__ ovfc,
        const unsigned short* __restrict__ F2, float* __restrict__ RS2,
        const float* __restrict__ EL2, const float* __restrict__ ER2,
        float* __restrict__ out) {
    __shared__ float sWd1[C1 * D2];
    __shared__ float sWd2[C1];
    __shared__ float sSd[C1], sRd[C1];
    __shared__ float sSc2[D2], sRc2[D2];
    __shared__ float sH2[8 * D2];
    int t = threadIdx.x;
    int bf = *flag;
    for (int u = t; u < C1 * D2; u += 256) sWd1[u] = ldw(Wd1, u, bf);
    for (int u = t; u < C1; u += 256) {
        sWd2[u] = ldw(Wd2, u, bf);
        sSd[u] = cst[CST_SD + u]; sRd[u] = cst[CST_RD + u];
    }
    if (t < D2) { sSc2[t] = cst[CST_SC2 + t]; sRc2[t] = cst[CST_RC2 + t]; }
    __syncthreads();

    int i = (blockIdx.x * 256 + t) >> 5;
    int l = t & 31;
    int nb = t >> 5;

    float eri = ER2[i];
    int dr = degp[i << 4];
    int dcap = dr < CAP ? dr : CAP;
    const unsigned short* row = &esrc2[i * CAP];
    float aF0 = 0.f, aF1 = 0.f, aF2 = 0.f, aF3 = 0.f, aF4 = 0.f, aF5 = 0.f, aF6 = 0.f, aF7 = 0.f;
    float S0 = 0.f, S1 = 0.f, S2 = 0.f, S3 = 0.f, S4 = 0.f, S5 = 0.f, S6 = 0.f, S7 = 0.f;
    int j = 0;
    for (; j + 7 < dcap; j += 8) {
        uint4 qq = *(const uint4*)&row[j];
        int s0 = qq.x & 0xFFFF, s1 = qq.x >> 16;
        int s2 = qq.y & 0xFFFF, s3 = qq.y >> 16;
        int s4 = qq.z & 0xFFFF, s5 = qq.z >> 16;
        int s6 = qq.w & 0xFFFF, s7 = qq.w >> 16;
        float w0 = __expf(lrelu(EL2[s0] + eri));
        float w1 = __expf(lrelu(EL2[s1] + eri));
        float w2 = __expf(lrelu(EL2[s2] + eri));
        float w3 = __expf(lrelu(EL2[s3] + eri));
        float w4 = __expf(lrelu(EL2[s4] + eri));
        float w5 = __expf(lrelu(EL2[s5] + eri));
        float w6 = __expf(lrelu(EL2[s6] + eri));
        float w7 = __expf(lrelu(EL2[s7] + eri));
        float v0 = bu2f(F2[(size_t)s0 * D2 + l]);
        float v1 = bu2f(F2[(size_t)s1 * D2 + l]);
        float v2 = bu2f(F2[(size_t)s2 * D2 + l]);
        float v3 = bu2f(F2[(size_t)s3 * D2 + l]);
        float v4 = bu2f(F2[(size_t)s4 * D2 + l]);
        float v5 = bu2f(F2[(size_t)s5 * D2 + l]);
        float v6 = bu2f(F2[(size_t)s6 * D2 + l]);
        float v7 = bu2f(F2[(size_t)s7 * D2 + l]);
        S0 += w0; S1 += w1; S2 += w2; S3 += w3;
        S4 += w4; S5 += w5; S6 += w6; S7 += w7;
        aF0 = fmaf(w0, v0, aF0); aF1 = fmaf(w1, v1, aF1);
        aF2 = fmaf(w2, v2, aF2); aF3 = fmaf(w3, v3, aF3);
        aF4 = fmaf(w4, v4, aF4); aF5 = fmaf(w5, v5, aF5);
        aF6 = fmaf(w6, v6, aF6); aF7 = fmaf(w7, v7, aF7);
    }
    for (; j + 3 < dcap; j += 4) {
        ushort4 q = *(const ushort4*)&row[j];
        int sA = q.x, sB = q.y, sC = q.z, sD = q.w;
        float wA = __expf(lrelu(EL2[sA] + eri));
        float wB = __expf(lrelu(EL2[sB] + eri));
        float wC = __expf(lrelu(EL2[sC] + eri));
        float wD = __expf(lrelu(EL2[sD] + eri));
        float vA = bu2f(F2[(size_t)sA * D2 + l]);
        float vB = bu2f(F2[(size_t)sB * D2 + l]);
        float vC = bu2f(F2[(size_t)sC * D2 + l]);
        float vD = bu2f(F2[(size_t)sD * D2 + l]);
        S0 += wA; S1 += wB; S2 += wC; S3 += wD;
        aF0 = fmaf(wA, vA, aF0); aF1 = fmaf(wB, vB, aF1);
        aF2 = fmaf(wC, vC, aF2); aF3 = fmaf(wD, vD, aF3);
    }
    for (; j < dcap; ++j) {
        int sA = (int)row[j];
        float wA = __expf(lrelu(EL2[sA] + eri));
        S0 += wA;
        aF0 = fmaf(wA, bu2f(F2[(size_t)sA * D2 + l]), aF0);
    }
    if (dr > CAP) {
        int novf = *ovfc;
        for (int p = 0; p < novf; ++p) {
            int2 o = ovf[p];
            if (o.x == i) {
                float wA = __expf(lrelu(EL2[o.y] + eri));
                S0 += wA;
                aF0 = fmaf(wA, bu2f(F2[(size_t)o.y * D2 + l]), aF0);
            }
        }
    }
    float S = ((S0 + S1) + (S2 + S3)) + ((S4 + S5) + (S6 + S7));
    float aF = ((aF0 + aF1) + (aF2 + aF3)) + ((aF4 + aF5) + (aF6 + aF7));
    float inv = S > 0.0f ? 1.0f / S : 0.0f;

    float h2 = fmaxf((aF * inv + RS2[(size_t)i * D2 + l]) * sSc2[l] + sRc2[l], 0.0f);
    RS2[(size_t)i * D2 + l] = h2;

    sH2[nb * D2 + l] = h2;
    float ac0 = 0.0f, ac1 = 0.0f, ac2 = 0.0f, ac3 = 0.0f;
#pragma unroll
    for (int d = 0; d < D2; ++d) {
        float h = sH2[nb * D2 + d];
        const float* wr = &sWd1[d * C1 + l];
        ac0 = fmaf(h, wr[0],  ac0);
        ac1 = fmaf(h, wr[32], ac1);
        ac2 = fmaf(h, wr[64], ac2);
        ac3 = fmaf(h, wr[96], ac3);
    }
    float rec = fmaxf(ac0 * sSd[l]      + sRd[l],      0.0f) * sWd2[l]
              + fmaxf(ac1 * sSd[l + 32] + sRd[l + 32], 0.0f) * sWd2[l + 32]
              + fmaxf(ac2 * sSd[l + 64] + sRd[l + 64], 0.0f) * sWd2[l + 64]
              + fmaxf(ac3 * sSd[l + 96] + sRd[l + 96], 0.0f) * sWd2[l + 96];
#pragma unroll
    for (int m = 16; m >= 1; m >>= 1) rec += __shfl_xor(rec, m);
    if (l == 0) out[NG * D2 + i] = rec + ldw(bd2, 0, bf);
}

// ---------------- graph mean pool: 32 rows x float4 ----------------
__global__ __launch_bounds__(256) void k_pool2(const int* __restrict__ gid,
                                               const float* __restrict__ H2,
                                               float* __restrict__ out) {
    __shared__ int sLo, sHi;
    __shared__ float sAcc[32 * 32];
    int g = blockIdx.x;
    int t = threadIdx.x;
    if (t == 0) {
        int lo = 0, hi = NN;
        while (lo < hi) { int m = (lo + hi) >> 1; if (gid[m] < g) lo = m + 1; else hi = m; }
        sLo = lo;
        lo = 0; hi = NN;
        while (lo < hi) { int m = (lo + hi) >> 1; if (gid[m] < g + 1) lo = m + 1; else hi = m; }
        sHi = lo;
    }
    __syncthreads();
    int lo = sLo, hi = sHi;
    int q = t & 7;
    int row = t >> 3;
    float4 acc = make_float4(0.f, 0.f, 0.f, 0.f);
    for (int i = lo + row; i < hi; i += 32) {
        float4 v = ((const float4*)&H2[(size_t)i * D2])[q];
        acc.x += v.x; acc.y += v.y; acc.z += v.z; acc.w += v.w;
    }
    *(float4*)&sAcc[row * 32 + 4 * q] = acc;
    __syncthreads();
    if (t < 32) {
        float a = 0.0f;
        for (int r = 0; r < 32; ++r) a += sAcc[r * 32 + t];
        float c = (float)(hi - lo);
        out[g * D2 + t] = a / fmaxf(c, 1.0f);
    }
}

extern "C" void kernel_launch(void* const* d_in, const int* in_sizes, int n_in,
                              void* d_out, int out_size, void* d_ws, size_t ws_size,
                              hipStream_t stream) {
    const void* feat = d_in[0];
    const void* W1 = d_in[1];  const void* al1 = d_in[2];  const void* ar1 = d_in[3];
    const void* res1 = d_in[4]; const void* b1 = d_in[5];
    const void* g1g = d_in[6]; const void* g1b = d_in[7];
    const void* g1m = d_in[8]; const void* g1v = d_in[9];
    const void* W2 = d_in[10]; const void* al2 = d_in[11]; const void* ar2 = d_in[12];
    const void* res2 = d_in[13]; const void* b2v = d_in[14];
    const void* g2g = d_in[15]; const void* g2b = d_in[16];
    const void* g2m = d_in[17]; const void* g2v = d_in[18];
    const void* Wd1 = d_in[19]; const void* bd1 = d_in[20];
    const void* gdg = d_in[21]; const void* gdb = d_in[22];
    const void* gdm = d_in[23]; const void* gdv = d_in[24];
    const void* Wd2 = d_in[25]; const void* bd2 = d_in[26];
    const int* src = (const int*)d_in[27];
    const int* dst = (const int*)d_in[28];
    const int* gid = (const int*)d_in[29];

    unsigned int* wsu = (unsigned int*)d_ws;
    int* degp   = (int*)(wsu + UO_DEGP);
    int* ovfc   = (int*)(wsu + UO_OVFC);
    int* flag   = (int*)(wsu + UO_FLAG);
    float* cst  = (float*)(wsu + UO_CST);
    unsigned short* esrc2 = (unsigned short*)(wsu + UO_ESRC2);
    int2* ovf   = (int2*)(wsu + UO_OVF);
    float* fcan = (float*)(wsu + UO_FCAN);
    unsigned short* F2 = (unsigned short*)(wsu + UO_F2);
    float* RS2  = (float*)(wsu + UO_RS2);
    float* EL2  = (float*)(wsu + UO_EL2);
    float* ER2  = (float*)(wsu + UO_ER2);

    hipMemsetAsync(d_ws, 0, (size_t)ZERO_UNITS * 4, stream);

    k_prep<<<NCH * 8, 256, 0, stream>>>(feat, dst, src, fcan, degp,
                                        esrc2, ovf, ovfc,
                                        W1, al1, ar1, res1, b1,
                                        g1g, g1b, g1m, g1v,
                                        b2v, g2g, g2b, g2m, g2v,
                                        bd1, gdg, gdb, gdm, gdv,
                                        flag, cst);

    k_layer1<<<(NN + 31) / 32, 256, 0, stream>>>(fcan, W2, res2, al2, ar2, flag, cst,
                                                 degp, esrc2, ovf, ovfc,
                                                 F2, RS2, EL2, ER2);

    k_final<<<(NN * 32) / 256, 256, 0, stream>>>(Wd1, Wd2, bd2, flag, cst,
                                                 degp, esrc2, ovf, ovfc,
                                                 F2, RS2, EL2, ER2,
                                                 (float*)d_out);

    k_pool2<<<NG, 256, 0, stream>>>(gid, RS2, (float*)d_out);
}

// Round 21
// 247.394 us; speedup vs baseline: 1.1917x; 1.0390x over previous
//
#include <hip/hip_runtime.h>
#include <hip/hip_bf16.h>
#include <hip/hip_fp16.h>

#define NN 50000
#define NE 800000
#define NG 64
#define C1 128    // H1*D1
#define D2 32
#define CAP 32    // capped slots per node; overflow handled exactly via ovf buffer
#define RNG 6250  // NN/8: dst-range width per XCD partition
#define NCH 391   // ceil(NE/2048) edge chunks
#define BN_EPS 1e-5f

// ---- constant-block layout (float offsets inside cst) ----
#define CST_A   0
#define CST_B   2
#define CST_P   4
#define CST_Q   132
#define CST_R   260
#define CST_SC2 388
#define CST_RC2 420
#define CST_SD  452
#define CST_RD  580
#define CST_N   1024

// ---- workspace layout (4-byte-unit offsets inside d_ws), ~23 MiB (ws is 256 MB) ----
#define UO_DEGP  0                        // int[16*NN] padded: one counter per 64B line (zeroed)
#define UO_OVFC  800000                   // int[1]   (zeroed)
#define ZERO_UNITS 800004
#define UO_FLAG  800004                   // int[1]
#define UO_CST   800008                   // float[CST_N]
#define UO_ESRC2 801040                   // ushort[CAP*NN] padded edge table (64B-aligned rows)
#define UO_OVF   1601040                  // int2[NE] overflow (dst,src)
#define UO_FCAN  3201040                  // float[NN]
#define UO_F2    3251040                  // ushort[D2*NN] bf16 (16B aligned)
#define UO_RS2   4051040                  // float[D2*NN]; overwritten with h2 by k_final
#define UO_EL2   5651040                  // float[NN]
#define UO_ER2   5701040                  // float[NN]
#define UO_END   5751040

typedef _Float16 h2vec __attribute__((ext_vector_type(2)));

__device__ __forceinline__ float lrelu(float x) { return fmaxf(x, 0.2f * x); }
__device__ __forceinline__ float bu2f(unsigned int u) {
    union { unsigned int i; float f; } v; v.i = (u & 0xFFFFu) << 16; return v.f;
}
__device__ __forceinline__ unsigned short f2bu(float f) {
    union { float f; unsigned int i; } v; v.f = f;
    unsigned int r = v.i + 0x7FFFu + ((v.i >> 16) & 1u);
    return (unsigned short)(r >> 16);
}
// pack two floats as f16 pair in one uint
__device__ __forceinline__ unsigned int packh2(float a, float b) {
    h2vec h; h.x = (_Float16)a; h.y = (_Float16)b;
    union { h2vec h; unsigned int u; } v; v.h = h; return v.u;
}
__device__ __forceinline__ h2vec as_h2(unsigned int u) {
    union { unsigned int u; h2vec h; } v; v.u = u; return v.h;
}
__device__ __forceinline__ float ldw(const void* p, int i, int bf) {
    return bf ? bu2f(((const unsigned short*)p)[i]) : ((const float*)p)[i];
}
__device__ __forceinline__ int sniff64(const unsigned int* fw, int l) {
    int cnt = 0;
    for (int j = l; j < 256; j += 64) {
        unsigned int b = (fw[j] >> 8) & 0x7Fu;
        cnt += (b >= 0x3Au && b <= 0x41u) ? 1 : 0;
    }
#pragma unroll
    for (int m = 32; m >= 1; m >>= 1) cnt += __shfl_xor(cnt, m);
    return (cnt > 128) ? 1 : 0;
}

// ---------------- edge-table build, XCD-range partitioned + fcan + const folding ----------------
__global__ void k_prep(const void* __restrict__ feat, const int* __restrict__ dst,
                       const int* __restrict__ src,
                       float* __restrict__ fcan, int* __restrict__ degp,
                       unsigned short* __restrict__ esrc2,
                       int2* __restrict__ ovf, int* __restrict__ ovfc,
                       const void* W1, const void* al1, const void* ar1,
                       const void* res1, const void* b1,
                       const void* g1g, const void* g1b, const void* g1m, const void* g1v,
                       const void* b2v, const void* g2g, const void* g2b,
                       const void* g2m, const void* g2v,
                       const void* bd1, const void* gdg, const void* gdb,
                       const void* gdm, const void* gdv,
                       int* __restrict__ flag, float* __restrict__ cst) {
    __shared__ int sBf;
    int t = threadIdx.x;
    if (t < 64) {
        int bf = sniff64((const unsigned int*)feat, t);
        if (t == 0) sBf = bf;
    }
    __syncthreads();
    int bf = sBf;
    int r = blockIdx.x & 7;
    int c = blockIdx.x >> 3;

    if (blockIdx.x == 0) {             // fold tiny weights into fp32 constants
        if (t == 0) *flag = bf;
        if (t < 128) {
            if (t < 2) {
                float a = 0.0f, b = 0.0f;
                for (int d = 0; d < 64; ++d) {
                    float w = ldw(W1, t * 64 + d, bf);
                    a += w * ldw(al1, t * 64 + d, bf);
                    b += w * ldw(ar1, t * 64 + d, bf);
                }
                cst[CST_A + t] = a;
                cst[CST_B + t] = b;
            }
            {
                float sc = rsqrtf(ldw(g1v, t, bf) + BN_EPS) * ldw(g1g, t, bf);
                cst[CST_P + t] = ldw(W1, t, bf) * sc;
                cst[CST_Q + t] = ldw(res1, t, bf) * sc;
                cst[CST_R + t] = (ldw(b1, t, bf) - ldw(g1m, t, bf)) * sc + ldw(g1b, t, bf);
            }
            if (t < D2) {
                float sc = rsqrtf(ldw(g2v, t, bf) + BN_EPS) * ldw(g2g, t, bf);
                cst[CST_SC2 + t] = sc;
                cst[CST_RC2 + t] = (ldw(b2v, t, bf) - ldw(g2m, t, bf)) * sc + ldw(g2b, t, bf);
            }
            {
                float sc = rsqrtf(ldw(gdv, t, bf) + BN_EPS) * ldw(gdg, t, bf);
                cst[CST_SD + t] = sc;
                cst[CST_RD + t] = (ldw(bd1, t, bf) - ldw(gdm, t, bf)) * sc + ldw(gdb, t, bf);
            }
        }
    }

    int lo = r * RNG, hi = lo + RNG;
#pragma unroll
    for (int j = 0; j < 8; ++j) {
        int k = c * 2048 + j * 256 + t;
        if (k < NE) {
            int d = dst[k];
            if (d >= lo && d < hi) {
                int slot = atomicAdd(&degp[d << 4], 1);
                if (slot < CAP) {
                    esrc2[d * CAP + slot] = (unsigned short)src[k];
                } else {
                    int p = atomicAdd(ovfc, 1);    // rare
                    ovf[p] = make_int2(d, src[k]);
                }
            }
        }
        if (r == 0 && k < NN) fcan[k] = ldw(feat, k, bf);
    }
}

// ---------------- layer-1: 32 nodes/block; f16-pair LDS + v_dot2_f32_f16 projection ----------------
__global__ __launch_bounds__(256) void k_layer1(
        const float* __restrict__ fcan, const void* W2, const void* res2,
        const void* al2, const void* ar2,
        const int* __restrict__ flag, const float* __restrict__ cst,
        const int* __restrict__ degp, const unsigned short* __restrict__ esrc2,
        const int2* __restrict__ ovf, const int* __restrict__ ovfc,
        unsigned short* __restrict__ F2, float* __restrict__ RS2,
        float* __restrict__ EL2, float* __restrict__ ER2) {
    __shared__ unsigned int sW2pk[32 * 66];  // [l][cw], (c,c+64) f16 pairs
    __shared__ unsigned int sR2pk[32 * 66];
    __shared__ unsigned int sH1pk[32 * 66];
    __shared__ float sP[C1], sQ[C1], sR[C1];
    __shared__ float sAl[D2], sAr[D2];
    int t = threadIdx.x;
    int bf = *flag;
    for (int u = t; u < 2048; u += 256) {
        int cw = u >> 5, l2 = u & 31;
        sW2pk[l2 * 66 + cw] = packh2(ldw(W2, cw * D2 + l2, bf),
                                     ldw(W2, (cw + 64) * D2 + l2, bf));
        sR2pk[l2 * 66 + cw] = packh2(ldw(res2, cw * D2 + l2, bf),
                                     ldw(res2, (cw + 64) * D2 + l2, bf));
    }
    if (t < C1) { sP[t] = cst[CST_P + t]; sQ[t] = cst[CST_Q + t]; sR[t] = cst[CST_R + t]; }
    if (t < D2) { sAl[t] = ldw(al2, t, bf); sAr[t] = ldw(ar2, t, bf); }
    __syncthreads();

    int l = t & 31;
    int g = t >> 5;
    int base = blockIdx.x * 32;
    float A0 = cst[CST_A + 0], A1 = cst[CST_A + 1];
    float B0 = cst[CST_B + 0], B1 = cst[CST_B + 1];

    int dcap[4], draw[4];
    float fiK[4];
#pragma unroll
    for (int k = 0; k < 4; ++k) {
        int i = base + g * 4 + k;
        if (i < NN) {
            draw[k] = degp[i << 4];
            dcap[k] = draw[k] < CAP ? draw[k] : CAP;
            fiK[k] = fcan[i];
        } else { draw[k] = 0; dcap[k] = 0; fiK[k] = 0.0f; }
    }
    float S0[4], S1[4], N0[4], N1[4];
#pragma unroll
    for (int k = 0; k < 4; ++k) { S0[k] = S1[k] = N0[k] = N1[k] = 0.0f; }
    int sA[4];
#pragma unroll
    for (int k = 0; k < 4; ++k)
        sA[k] = (l < dcap[k]) ? (int)esrc2[(base + g * 4 + k) * CAP + l] : 0;
    float fA[4];
#pragma unroll
    for (int k = 0; k < 4; ++k) fA[k] = fcan[sA[k]];
#pragma unroll
    for (int k = 0; k < 4; ++k) {
        if (l < dcap[k]) {
            float w0 = __expf(lrelu(A0 * fA[k] + B0 * fiK[k]));
            float w1 = __expf(lrelu(A1 * fA[k] + B1 * fiK[k]));
            S0[k] += w0; N0[k] += w0 * fA[k];
            S1[k] += w1; N1[k] += w1 * fA[k];
        }
    }
    // rare overflow edges (deg > CAP)
#pragma unroll
    for (int k = 0; k < 4; ++k) {
        if (draw[k] > CAP) {
            int i = base + g * 4 + k;
            int novf = *ovfc;
            for (int p = l; p < novf; p += 32) {
                int2 o = ovf[p];
                if (o.x == i) {
                    float fs = fcan[o.y];
                    float w0 = __expf(lrelu(A0 * fs + B0 * fiK[k]));
                    float w1 = __expf(lrelu(A1 * fs + B1 * fiK[k]));
                    S0[k] += w0; N0[k] += w0 * fs;
                    S1[k] += w1; N1[k] += w1 * fs;
                }
            }
        }
    }
#pragma unroll
    for (int m = 16; m >= 1; m >>= 1) {
#pragma unroll
        for (int k = 0; k < 4; ++k) {
            S0[k] += __shfl_xor(S0[k], m); N0[k] += __shfl_xor(N0[k], m);
            S1[k] += __shfl_xor(S1[k], m); N1[k] += __shfl_xor(N1[k], m);
        }
    }
#pragma unroll
    for (int k = 0; k < 4; ++k) {
        int slot = g * 4 + k;
        float T0 = S0[k] > 0.0f ? N0[k] / S0[k] : 0.0f;
        float T1 = S1[k] > 0.0f ? N1[k] / S1[k] : 0.0f;
        float h0  = fmaxf(sP[l]      * T0 + sQ[l]      * fiK[k] + sR[l],      0.0f);
        float h1v = fmaxf(sP[l + 32] * T0 + sQ[l + 32] * fiK[k] + sR[l + 32], 0.0f);
        float h2v = fmaxf(sP[l + 64] * T1 + sQ[l + 64] * fiK[k] + sR[l + 64], 0.0f);
        float h3v = fmaxf(sP[l + 96] * T1 + sQ[l + 96] * fiK[k] + sR[l + 96], 0.0f);
        sH1pk[slot * 66 + l]      = packh2(h0,  h2v);   // (c, c+64) f16 pair
        sH1pk[slot * 66 + l + 32] = packh2(h1v, h3v);
    }
    __syncthreads();

    // --- phase 2: v_dot2_f32_f16 — one inst per (c,c+64) pair, fp32 accumulate
    int w = t >> 6;
    int half = (t >> 5) & 1;
    int nb0 = w * 8 + half * 4;
    float aF[4] = {0.f, 0.f, 0.f, 0.f}, aR[4] = {0.f, 0.f, 0.f, 0.f};
    for (int cw = 0; cw < 64; cw += 2) {
        uint2 wq = *(const uint2*)&sW2pk[l * 66 + cw];
        uint2 rq = *(const uint2*)&sR2pk[l * 66 + cw];
#pragma unroll
        for (int n = 0; n < 4; ++n) {
            uint2 hq = *(const uint2*)&sH1pk[(nb0 + n) * 66 + cw];   // broadcast
            aF[n] = __builtin_amdgcn_fdot2(as_h2(hq.x), as_h2(wq.x),
                    __builtin_amdgcn_fdot2(as_h2(hq.y), as_h2(wq.y), aF[n], false), false);
            aR[n] = __builtin_amdgcn_fdot2(as_h2(hq.x), as_h2(rq.x),
                    __builtin_amdgcn_fdot2(as_h2(hq.y), as_h2(rq.y), aR[n], false), false);
        }
    }
#pragma unroll
    for (int n = 0; n < 4; ++n) {
        int i = base + nb0 + n;
        if (i < NN) {
            float elp = aF[n] * sAl[l], erp = aF[n] * sAr[l];
#pragma unroll
            for (int m = 16; m >= 1; m >>= 1) {
                elp += __shfl_xor(elp, m);
                erp += __shfl_xor(erp, m);
            }
            if (l == 0) { EL2[i] = elp; ER2[i] = erp; }
            F2[(size_t)i * D2 + l]  = f2bu(aF[n]);
            RS2[(size_t)i * D2 + l] = aR[n];
        }
    }
}

// ---------------- layer-2 gather (8 independent chains via uint4 row loads) + decoder ----------------
__global__ __launch_bounds__(256) void k_final(
        const void* Wd1, const void* Wd2, const void* bd2,
        const int* __restrict__ flag, const float* __restrict__ cst,
        const int* __restrict__ degp, const unsigned short* __restrict__ esrc2,
        const int2* __restrict__ ovf, const int* __restrict__ ovfc,
        const unsigned short* __restrict__ F2, float* __restrict__ RS2,
        const float* __restrict__ EL2, const float* __restrict__ ER2,
        float* __restrict__ out) {
    __shared__ float sWd1[C1 * D2];
    __shared__ float sWd2[C1];
    __shared__ float sSd[C1], sRd[C1];
    __shared__ float sSc2[D2], sRc2[D2];
    __shared__ float sH2[8 * D2];
    int t = threadIdx.x;
    int bf = *flag;
    for (int u = t; u < C1 * D2; u += 256) sWd1[u] = ldw(Wd1, u, bf);
    for (int u = t; u < C1; u += 256) {
        sWd2[u] = ldw(Wd2, u, bf);
        sSd[u] = cst[CST_SD + u]; sRd[u] = cst[CST_RD + u];
    }
    if (t < D2) { sSc2[t] = cst[CST_SC2 + t]; sRc2[t] = cst[CST_RC2 + t]; }
    __syncthreads();

    int i = (blockIdx.x * 256 + t) >> 5;
    int l = t & 31;
    int nb = t >> 5;

    float eri = ER2[i];
    int dr = degp[i << 4];
    int dcap = dr < CAP ? dr : CAP;
    const unsigned short* row = &esrc2[i * CAP];
    float aF0 = 0.f, aF1 = 0.f, aF2 = 0.f, aF3 = 0.f, aF4 = 0.f, aF5 = 0.f, aF6 = 0.f, aF7 = 0.f;
    float S0 = 0.f, S1 = 0.f, S2 = 0.f, S3 = 0.f, S4 = 0.f, S5 = 0.f, S6 = 0.f, S7 = 0.f;
    int j = 0;
    for (; j + 7 < dcap; j += 8) {
        uint4 qq = *(const uint4*)&row[j];
        int s0 = qq.x & 0xFFFF, s1 = qq.x >> 16;
        int s2 = qq.y & 0xFFFF, s3 = qq.y >> 16;
        int s4 = qq.z & 0xFFFF, s5 = qq.z >> 16;
        int s6 = qq.w & 0xFFFF, s7 = qq.w >> 16;
        float w0 = __expf(lrelu(EL2[s0] + eri));
        float w1 = __expf(lrelu(EL2[s1] + eri));
        float w2 = __expf(lrelu(EL2[s2] + eri));
        float w3 = __expf(lrelu(EL2[s3] + eri));
        float w4 = __expf(lrelu(EL2[s4] + eri));
        float w5 = __expf(lrelu(EL2[s5] + eri));
        float w6 = __expf(lrelu(EL2[s6] + eri));
        float w7 = __expf(lrelu(EL2[s7] + eri));
        float v0 = bu2f(F2[(size_t)s0 * D2 + l]);
        float v1 = bu2f(F2[(size_t)s1 * D2 + l]);
        float v2 = bu2f(F2[(size_t)s2 * D2 + l]);
        float v3 = bu2f(F2[(size_t)s3 * D2 + l]);
        float v4 = bu2f(F2[(size_t)s4 * D2 + l]);
        float v5 = bu2f(F2[(size_t)s5 * D2 + l]);
        float v6 = bu2f(F2[(size_t)s6 * D2 + l]);
        float v7 = bu2f(F2[(size_t)s7 * D2 + l]);
        S0 += w0; S1 += w1; S2 += w2; S3 += w3;
        S4 += w4; S5 += w5; S6 += w6; S7 += w7;
        aF0 = fmaf(w0, v0, aF0); aF1 = fmaf(w1, v1, aF1);
        aF2 = fmaf(w2, v2, aF2); aF3 = fmaf(w3, v3, aF3);
        aF4 = fmaf(w4, v4, aF4); aF5 = fmaf(w5, v5, aF5);
        aF6 = fmaf(w6, v6, aF6); aF7 = fmaf(w7, v7, aF7);
    }
    for (; j + 3 < dcap; j += 4) {
        ushort4 q = *(const ushort4*)&row[j];
        int sA = q.x, sB = q.y, sC = q.z, sD = q.w;
        float wA = __expf(lrelu(EL2[sA] + eri));
        float wB = __expf(lrelu(EL2[sB] + eri));
        float wC = __expf(lrelu(EL2[sC] + eri));
        float wD = __expf(lrelu(EL2[sD] + eri));
        float vA = bu2f(F2[(size_t)sA * D2 + l]);
        float vB = bu2f(F2[(size_t)sB * D2 + l]);
        float vC = bu2f(F2[(size_t)sC * D2 + l]);
        float vD = bu2f(F2[(size_t)sD * D2 + l]);
        S0 += wA; S1 += wB; S2 += wC; S3 += wD;
        aF0 = fmaf(wA, vA, aF0); aF1 = fmaf(wB, vB, aF1);
        aF2 = fmaf(wC, vC, aF2); aF3 = fmaf(wD, vD, aF3);
    }
    for (; j < dcap; ++j) {
        int sA = (int)row[j];
        float wA = __expf(lrelu(EL2[sA] + eri));
        S0 += wA;
        aF0 = fmaf(wA, bu2f(F2[(size_t)sA * D2 + l]), aF0);
    }
    if (dr > CAP) {
        int novf = *ovfc;
        for (int p = 0; p < novf; ++p) {
            int2 o = ovf[p];
            if (o.x == i) {
                float wA = __expf(lrelu(EL2[o.y] + eri));
                S0 += wA;
                aF0 = fmaf(wA, bu2f(F2[(size_t)o.y * D2 + l]), aF0);
            }
        }
    }
    float S = ((S0 + S1) + (S2 + S3)) + ((S4 + S5) + (S6 + S7));
    float aF = ((aF0 + aF1) + (aF2 + aF3)) + ((aF4 + aF5) + (aF6 + aF7));
    float inv = S > 0.0f ? 1.0f / S : 0.0f;

    float h2 = fmaxf((aF * inv + RS2[(size_t)i * D2 + l]) * sSc2[l] + sRc2[l], 0.0f);
    RS2[(size_t)i * D2 + l] = h2;

    sH2[nb * D2 + l] = h2;
    float ac0 = 0.0f, ac1 = 0.0f, ac2 = 0.0f, ac3 = 0.0f;
#pragma unroll
    for (int d = 0; d < D2; ++d) {
        float h = sH2[nb * D2 + d];
        const float* wr = &sWd1[d * C1 + l];
        ac0 = fmaf(h, wr[0],  ac0);
        ac1 = fmaf(h, wr[32], ac1);
        ac2 = fmaf(h, wr[64], ac2);
        ac3 = fmaf(h, wr[96], ac3);
    }
    float rec = fmaxf(ac0 * sSd[l]      + sRd[l],      0.0f) * sWd2[l]
              + fmaxf(ac1 * sSd[l + 32] + sRd[l + 32], 0.0f) * sWd2[l + 32]
              + fmaxf(ac2 * sSd[l + 64] + sRd[l + 64], 0.0f) * sWd2[l + 64]
              + fmaxf(ac3 * sSd[l + 96] + sRd[l + 96], 0.0f) * sWd2[l + 96];
#pragma unroll
    for (int m = 16; m >= 1; m >>= 1) rec += __shfl_xor(rec, m);
    if (l == 0) out[NG * D2 + i] = rec + ldw(bd2, 0, bf);
}

// ---------------- graph mean pool: 32 rows x float4 ----------------
__global__ __launch_bounds__(256) void k_pool2(const int* __restrict__ gid,
                                               const float* __restrict__ H2,
                                               float* __restrict__ out) {
    __shared__ int sLo, sHi;
    __shared__ float sAcc[32 * 32];
    int g = blockIdx.x;
    int t = threadIdx.x;
    if (t == 0) {
        int lo = 0, hi = NN;
        while (lo < hi) { int m = (lo + hi) >> 1; if (gid[m] < g) lo = m + 1; else hi = m; }
        sLo = lo;
        lo = 0; hi = NN;
        while (lo < hi) { int m = (lo + hi) >> 1; if (gid[m] < g + 1) lo = m + 1; else hi = m; }
        sHi = lo;
    }
    __syncthreads();
    int lo = sLo, hi = sHi;
    int q = t & 7;
    int row = t >> 3;
    float4 acc = make_float4(0.f, 0.f, 0.f, 0.f);
    for (int i = lo + row; i < hi; i += 32) {
        float4 v = ((const float4*)&H2[(size_t)i * D2])[q];
        acc.x += v.x; acc.y += v.y; acc.z += v.z; acc.w += v.w;
    }
    *(float4*)&sAcc[row * 32 + 4 * q] = acc;
    __syncthreads();
    if (t < 32) {
        float a = 0.0f;
        for (int r = 0; r < 32; ++r) a += sAcc[r * 32 + t];
        float c = (float)(hi - lo);
        out[g * D2 + t] = a / fmaxf(c, 1.0f);
    }
}

extern "C" void kernel_launch(void* const* d_in, const int* in_sizes, int n_in,
                              void* d_out, int out_size, void* d_ws, size_t ws_size,
                              hipStream_t stream) {
    const void* feat = d_in[0];
    const void* W1 = d_in[1];  const void* al1 = d_in[2];  const void* ar1 = d_in[3];
    const void* res1 = d_in[4]; const void* b1 = d_in[5];
    const void* g1g = d_in[6]; const void* g1b = d_in[7];
    const void* g1m = d_in[8]; const void* g1v = d_in[9];
    const void* W2 = d_in[10]; const void* al2 = d_in[11]; const void* ar2 = d_in[12];
    const void* res2 = d_in[13]; const void* b2v = d_in[14];
    const void* g2g = d_in[15]; const void* g2b = d_in[16];
    const void* g2m = d_in[17]; const void* g2v = d_in[18];
    const void* Wd1 = d_in[19]; const void* bd1 = d_in[20];
    const void* gdg = d_in[21]; const void* gdb = d_in[22];
    const void* gdm = d_in[23]; const void* gdv = d_in[24];
    const void* Wd2 = d_in[25]; const void* bd2 = d_in[26];
    const int* src = (const int*)d_in[27];
    const int* dst = (const int*)d_in[28];
    const int* gid = (const int*)d_in[29];

    unsigned int* wsu = (unsigned int*)d_ws;
    int* degp   = (int*)(wsu + UO_DEGP);
    int* ovfc   = (int*)(wsu + UO_OVFC);
    int* flag   = (int*)(wsu + UO_FLAG);
    float* cst  = (float*)(wsu + UO_CST);
    unsigned short* esrc2 = (unsigned short*)(wsu + UO_ESRC2);
    int2* ovf   = (int2*)(wsu + UO_OVF);
    float* fcan = (float*)(wsu + UO_FCAN);
    unsigned short* F2 = (unsigned short*)(wsu + UO_F2);
    float* RS2  = (float*)(wsu + UO_RS2);
    float* EL2  = (float*)(wsu + UO_EL2);
    float* ER2  = (float*)(wsu + UO_ER2);

    hipMemsetAsync(d_ws, 0, (size_t)ZERO_UNITS * 4, stream);

    k_prep<<<NCH * 8, 256, 0, stream>>>(feat, dst, src, fcan, degp,
                                        esrc2, ovf, ovfc,
                                        W1, al1, ar1, res1, b1,
                                        g1g, g1b, g1m, g1v,
                                        b2v, g2g, g2b, g2m, g2v,
                                        bd1, gdg, gdb, gdm, gdv,
                                        flag, cst);

    k_layer1<<<(NN + 31) / 32, 256, 0, stream>>>(fcan, W2, res2, al2, ar2, flag, cst,
                                                 degp, esrc2, ovf, ovfc,
                                                 F2, RS2, EL2, ER2);

    k_final<<<(NN * 32) / 256, 256, 0, stream>>>(Wd1, Wd2, bd2, flag, cst,
                                                 degp, esrc2, ovf, ovfc,
                                                 F2, RS2, EL2, ER2,
                                                 (float*)d_out);

    k_pool2<<<NG, 256, 0, stream>>>(gid, RS2, (float*)d_out);
}

// Round 22
// 245.550 us; speedup vs baseline: 1.2007x; 1.0075x over previous
//
#include <hip/hip_runtime.h>
#include <hip/hip_bf16.h>
#include <hip/hip_fp16.h>

#define NN 50000
#define NE 800000
#define NG 64
#define C1 128    // H1*D1
#define D2 32
#define CAP 32    // capped slots per node; overflow handled exactly via ovf buffer
#define RNG 6250  // NN/8: dst-range width per XCD partition
#define NCH 391   // ceil(NE/2048) edge chunks
#define BN_EPS 1e-5f

// ---- constant-block layout (float offsets inside cst) ----
#define CST_A   0
#define CST_B   2
#define CST_P   4
#define CST_Q   132
#define CST_R   260
#define CST_SC2 388
#define CST_RC2 420
#define CST_SD  452
#define CST_RD  580
#define CST_N   1024

// ---- workspace layout (4-byte-unit offsets inside d_ws), ~23 MiB (ws is 256 MB) ----
#define UO_DEGP  0                        // int[16*NN] padded: one counter per 64B line (zeroed)
#define UO_OVFC  800000                   // int[1]   (zeroed)
#define ZERO_UNITS 800004
#define UO_FLAG  800004                   // int[1]
#define UO_CST   800008                   // float[CST_N]
#define UO_ESRC2 801040                   // ushort[CAP*NN] padded edge table (64B-aligned rows)
#define UO_OVF   1601040                  // int2[NE] overflow (dst,src)
#define UO_FCAN  3201040                  // float[NN]
#define UO_F2    3251040                  // ushort[D2*NN] bf16 (16B aligned)
#define UO_RS2   4051040                  // float[D2*NN]; overwritten with h2 by k_final
#define UO_EL2   5651040                  // float[NN]
#define UO_ER2   5701040                  // float[NN]
#define UO_END   5751040

typedef _Float16 h2vec __attribute__((ext_vector_type(2)));

__device__ __forceinline__ float lrelu(float x) { return fmaxf(x, 0.2f * x); }
__device__ __forceinline__ float bu2f(unsigned int u) {
    union { unsigned int i; float f; } v; v.i = (u & 0xFFFFu) << 16; return v.f;
}
__device__ __forceinline__ unsigned short f2bu(float f) {
    union { float f; unsigned int i; } v; v.f = f;
    unsigned int r = v.i + 0x7FFFu + ((v.i >> 16) & 1u);
    return (unsigned short)(r >> 16);
}
// pack two floats as f16 pair in one uint
__device__ __forceinline__ unsigned int packh2(float a, float b) {
    h2vec h; h.x = (_Float16)a; h.y = (_Float16)b;
    union { h2vec h; unsigned int u; } v; v.h = h; return v.u;
}
__device__ __forceinline__ h2vec as_h2(unsigned int u) {
    union { unsigned int u; h2vec h; } v; v.u = u; return v.h;
}
__device__ __forceinline__ float ldw(const void* p, int i, int bf) {
    return bf ? bu2f(((const unsigned short*)p)[i]) : ((const float*)p)[i];
}
__device__ __forceinline__ int sniff64(const unsigned int* fw, int l) {
    int cnt = 0;
    for (int j = l; j < 256; j += 64) {
        unsigned int b = (fw[j] >> 8) & 0x7Fu;
        cnt += (b >= 0x3Au && b <= 0x41u) ? 1 : 0;
    }
#pragma unroll
    for (int m = 32; m >= 1; m >>= 1) cnt += __shfl_xor(cnt, m);
    return (cnt > 128) ? 1 : 0;
}

// ---------------- edge-table build, XCD-range partitioned + fcan + const folding ----------------
__global__ void k_prep(const void* __restrict__ feat, const int* __restrict__ dst,
                       const int* __restrict__ src,
                       float* __restrict__ fcan, int* __restrict__ degp,
                       unsigned short* __restrict__ esrc2,
                       int2* __restrict__ ovf, int* __restrict__ ovfc,
                       const void* W1, const void* al1, const void* ar1,
                       const void* res1, const void* b1,
                       const void* g1g, const void* g1b, const void* g1m, const void* g1v,
                       const void* b2v, const void* g2g, const void* g2b,
                       const void* g2m, const void* g2v,
                       const void* bd1, const void* gdg, const void* gdb,
                       const void* gdm, const void* gdv,
                       int* __restrict__ flag, float* __restrict__ cst) {
    __shared__ int sBf;
    int t = threadIdx.x;
    if (t < 64) {
        int bf = sniff64((const unsigned int*)feat, t);
        if (t == 0) sBf = bf;
    }
    __syncthreads();
    int bf = sBf;
    int r = blockIdx.x & 7;
    int c = blockIdx.x >> 3;

    if (blockIdx.x == 0) {             // fold tiny weights into fp32 constants
        if (t == 0) *flag = bf;
        if (t < 128) {
            if (t < 2) {
                float a = 0.0f, b = 0.0f;
                for (int d = 0; d < 64; ++d) {
                    float w = ldw(W1, t * 64 + d, bf);
                    a += w * ldw(al1, t * 64 + d, bf);
                    b += w * ldw(ar1, t * 64 + d, bf);
                }
                cst[CST_A + t] = a;
                cst[CST_B + t] = b;
            }
            {
                float sc = rsqrtf(ldw(g1v, t, bf) + BN_EPS) * ldw(g1g, t, bf);
                cst[CST_P + t] = ldw(W1, t, bf) * sc;
                cst[CST_Q + t] = ldw(res1, t, bf) * sc;
                cst[CST_R + t] = (ldw(b1, t, bf) - ldw(g1m, t, bf)) * sc + ldw(g1b, t, bf);
            }
            if (t < D2) {
                float sc = rsqrtf(ldw(g2v, t, bf) + BN_EPS) * ldw(g2g, t, bf);
                cst[CST_SC2 + t] = sc;
                cst[CST_RC2 + t] = (ldw(b2v, t, bf) - ldw(g2m, t, bf)) * sc + ldw(g2b, t, bf);
            }
            {
                float sc = rsqrtf(ldw(gdv, t, bf) + BN_EPS) * ldw(gdg, t, bf);
                cst[CST_SD + t] = sc;
                cst[CST_RD + t] = (ldw(bd1, t, bf) - ldw(gdm, t, bf)) * sc + ldw(gdb, t, bf);
            }
        }
    }

    int lo = r * RNG, hi = lo + RNG;
#pragma unroll
    for (int j = 0; j < 8; ++j) {
        int k = c * 2048 + j * 256 + t;
        if (k < NE) {
            int d = dst[k];
            if (d >= lo && d < hi) {
                int slot = atomicAdd(&degp[d << 4], 1);
                if (slot < CAP) {
                    esrc2[d * CAP + slot] = (unsigned short)src[k];
                } else {
                    int p = atomicAdd(ovfc, 1);    // rare
                    ovf[p] = make_int2(d, src[k]);
                }
            }
        }
        if (r == 0 && k < NN) fcan[k] = ldw(feat, k, bf);
    }
}

// ---------------- layer-1: 32 nodes/block; f16-pair LDS + v_dot2_f32_f16 projection ----------------
__global__ __launch_bounds__(256) void k_layer1(
        const float* __restrict__ fcan, const void* W2, const void* res2,
        const void* al2, const void* ar2,
        const int* __restrict__ flag, const float* __restrict__ cst,
        const int* __restrict__ degp, const unsigned short* __restrict__ esrc2,
        const int2* __restrict__ ovf, const int* __restrict__ ovfc,
        unsigned short* __restrict__ F2, float* __restrict__ RS2,
        float* __restrict__ EL2, float* __restrict__ ER2) {
    __shared__ unsigned int sW2pk[32 * 66];  // [l][cw], (c,c+64) f16 pairs
    __shared__ unsigned int sR2pk[32 * 66];
    __shared__ unsigned int sH1pk[32 * 66];
    __shared__ float sP[C1], sQ[C1], sR[C1];
    __shared__ float sAl[D2], sAr[D2];
    int t = threadIdx.x;
    int bf = *flag;
    for (int u = t; u < 2048; u += 256) {
        int cw = u >> 5, l2 = u & 31;
        sW2pk[l2 * 66 + cw] = packh2(ldw(W2, cw * D2 + l2, bf),
                                     ldw(W2, (cw + 64) * D2 + l2, bf));
        sR2pk[l2 * 66 + cw] = packh2(ldw(res2, cw * D2 + l2, bf),
                                     ldw(res2, (cw + 64) * D2 + l2, bf));
    }
    if (t < C1) { sP[t] = cst[CST_P + t]; sQ[t] = cst[CST_Q + t]; sR[t] = cst[CST_R + t]; }
    if (t < D2) { sAl[t] = ldw(al2, t, bf); sAr[t] = ldw(ar2, t, bf); }
    __syncthreads();

    int l = t & 31;
    int g = t >> 5;
    int base = blockIdx.x * 32;
    float A0 = cst[CST_A + 0], A1 = cst[CST_A + 1];
    float B0 = cst[CST_B + 0], B1 = cst[CST_B + 1];

    int dcap[4], draw[4];
    float fiK[4];
#pragma unroll
    for (int k = 0; k < 4; ++k) {
        int i = base + g * 4 + k;
        if (i < NN) {
            draw[k] = degp[i << 4];
            dcap[k] = draw[k] < CAP ? draw[k] : CAP;
            fiK[k] = fcan[i];
        } else { draw[k] = 0; dcap[k] = 0; fiK[k] = 0.0f; }
    }
    float S0[4], S1[4], N0[4], N1[4];
#pragma unroll
    for (int k = 0; k < 4; ++k) { S0[k] = S1[k] = N0[k] = N1[k] = 0.0f; }
    int sA[4];
#pragma unroll
    for (int k = 0; k < 4; ++k)
        sA[k] = (l < dcap[k]) ? (int)esrc2[(base + g * 4 + k) * CAP + l] : 0;
    float fA[4];
#pragma unroll
    for (int k = 0; k < 4; ++k) fA[k] = fcan[sA[k]];
#pragma unroll
    for (int k = 0; k < 4; ++k) {
        if (l < dcap[k]) {
            float w0 = __expf(lrelu(A0 * fA[k] + B0 * fiK[k]));
            float w1 = __expf(lrelu(A1 * fA[k] + B1 * fiK[k]));
            S0[k] += w0; N0[k] += w0 * fA[k];
            S1[k] += w1; N1[k] += w1 * fA[k];
        }
    }
    // rare overflow edges (deg > CAP)
#pragma unroll
    for (int k = 0; k < 4; ++k) {
        if (draw[k] > CAP) {
            int i = base + g * 4 + k;
            int novf = *ovfc;
            for (int p = l; p < novf; p += 32) {
                int2 o = ovf[p];
                if (o.x == i) {
                    float fs = fcan[o.y];
                    float w0 = __expf(lrelu(A0 * fs + B0 * fiK[k]));
                    float w1 = __expf(lrelu(A1 * fs + B1 * fiK[k]));
                    S0[k] += w0; N0[k] += w0 * fs;
                    S1[k] += w1; N1[k] += w1 * fs;
                }
            }
        }
    }
#pragma unroll
    for (int m = 16; m >= 1; m >>= 1) {
#pragma unroll
        for (int k = 0; k < 4; ++k) {
            S0[k] += __shfl_xor(S0[k], m); N0[k] += __shfl_xor(N0[k], m);
            S1[k] += __shfl_xor(S1[k], m); N1[k] += __shfl_xor(N1[k], m);
        }
    }
#pragma unroll
    for (int k = 0; k < 4; ++k) {
        int slot = g * 4 + k;
        float T0 = S0[k] > 0.0f ? N0[k] / S0[k] : 0.0f;
        float T1 = S1[k] > 0.0f ? N1[k] / S1[k] : 0.0f;
        float h0  = fmaxf(sP[l]      * T0 + sQ[l]      * fiK[k] + sR[l],      0.0f);
        float h1v = fmaxf(sP[l + 32] * T0 + sQ[l + 32] * fiK[k] + sR[l + 32], 0.0f);
        float h2v = fmaxf(sP[l + 64] * T1 + sQ[l + 64] * fiK[k] + sR[l + 64], 0.0f);
        float h3v = fmaxf(sP[l + 96] * T1 + sQ[l + 96] * fiK[k] + sR[l + 96], 0.0f);
        sH1pk[slot * 66 + l]      = packh2(h0,  h2v);   // (c, c+64) f16 pair
        sH1pk[slot * 66 + l + 32] = packh2(h1v, h3v);
    }
    __syncthreads();

    // --- phase 2: v_dot2_f32_f16 — one inst per (c,c+64) pair, fp32 accumulate
    int w = t >> 6;
    int half = (t >> 5) & 1;
    int nb0 = w * 8 + half * 4;
    float aF[4] = {0.f, 0.f, 0.f, 0.f}, aR[4] = {0.f, 0.f, 0.f, 0.f};
    for (int cw = 0; cw < 64; cw += 2) {
        uint2 wq = *(const uint2*)&sW2pk[l * 66 + cw];
        uint2 rq = *(const uint2*)&sR2pk[l * 66 + cw];
#pragma unroll
        for (int n = 0; n < 4; ++n) {
            uint2 hq = *(const uint2*)&sH1pk[(nb0 + n) * 66 + cw];   // broadcast
            aF[n] = __builtin_amdgcn_fdot2(as_h2(hq.x), as_h2(wq.x),
                    __builtin_amdgcn_fdot2(as_h2(hq.y), as_h2(wq.y), aF[n], false), false);
            aR[n] = __builtin_amdgcn_fdot2(as_h2(hq.x), as_h2(rq.x),
                    __builtin_amdgcn_fdot2(as_h2(hq.y), as_h2(rq.y), aR[n], false), false);
        }
    }
#pragma unroll
    for (int n = 0; n < 4; ++n) {
        int i = base + nb0 + n;
        if (i < NN) {
            float elp = aF[n] * sAl[l], erp = aF[n] * sAr[l];
#pragma unroll
            for (int m = 16; m >= 1; m >>= 1) {
                elp += __shfl_xor(elp, m);
                erp += __shfl_xor(erp, m);
            }
            if (l == 0) { EL2[i] = elp; ER2[i] = erp; }
            F2[(size_t)i * D2 + l]  = f2bu(aF[n]);
            RS2[(size_t)i * D2 + l] = aR[n];
        }
    }
}

// ---------------- layer-2 gather: per-lane w (exp once/edge) + LDS (w,s) broadcast ----------------
__global__ __launch_bounds__(256) void k_final(
        const void* Wd1, const void* Wd2, const void* bd2,
        const int* __restrict__ flag, const float* __restrict__ cst,
        const int* __restrict__ degp, const unsigned short* __restrict__ esrc2,
        const int2* __restrict__ ovf, const int* __restrict__ ovfc,
        const unsigned short* __restrict__ F2, float* __restrict__ RS2,
        const float* __restrict__ EL2, const float* __restrict__ ER2,
        float* __restrict__ out) {
    __shared__ float sWd1[C1 * D2];
    __shared__ float sWd2[C1];
    __shared__ float sSd[C1], sRd[C1];
    __shared__ float sSc2[D2], sRc2[D2];
    __shared__ float sH2[8 * D2];
    __shared__ unsigned int sWS[8 * 64];  // per-group (w,s) pairs: [nb][2*e], ds_read_b64 aligned
    int t = threadIdx.x;
    int bf = *flag;
    for (int u = t; u < C1 * D2; u += 256) sWd1[u] = ldw(Wd1, u, bf);
    for (int u = t; u < C1; u += 256) {
        sWd2[u] = ldw(Wd2, u, bf);
        sSd[u] = cst[CST_SD + u]; sRd[u] = cst[CST_RD + u];
    }
    if (t < D2) { sSc2[t] = cst[CST_SC2 + t]; sRc2[t] = cst[CST_RC2 + t]; }
    __syncthreads();

    int i = (blockIdx.x * 256 + t) >> 5;
    int l = t & 31;
    int nb = t >> 5;

    float eri = ER2[i];
    int dr = degp[i << 4];
    int dcap = dr < CAP ? dr : CAP;
    const unsigned short* row = &esrc2[i * CAP];

    // --- per-lane w: lane l owns edge l (exp computed ONCE per edge, not 32x)
    int sMy = 0; float wMy = 0.0f;
    if (l < dcap) {
        sMy = (int)row[l];                    // coalesced 64B row read
        wMy = __expf(lrelu(EL2[sMy] + eri));  // 32 independent gathers, one instruction
    }
    float S = wMy;
#pragma unroll
    for (int m = 16; m >= 1; m >>= 1) S += __shfl_xor(S, m);
    // stash (w,s) for broadcast reads (same-wave write->read, no barrier needed)
    sWS[nb * 64 + 2 * l]     = __float_as_uint(wMy);
    sWS[nb * 64 + 2 * l + 1] = (unsigned int)sMy;

    // --- dim-parallel accumulation: 1 ds_read_b64 broadcast + 1 gather + 1 fma per edge
    float aF0 = 0.f, aF1 = 0.f, aF2 = 0.f, aF3 = 0.f;
    int e = 0;
    for (; e + 3 < dcap; e += 4) {
        uint2 p0 = *(const uint2*)&sWS[nb * 64 + 2 * e];
        uint2 p1 = *(const uint2*)&sWS[nb * 64 + 2 * (e + 1)];
        uint2 p2 = *(const uint2*)&sWS[nb * 64 + 2 * (e + 2)];
        uint2 p3 = *(const uint2*)&sWS[nb * 64 + 2 * (e + 3)];
        float v0 = bu2f(F2[(size_t)p0.y * D2 + l]);
        float v1 = bu2f(F2[(size_t)p1.y * D2 + l]);
        float v2 = bu2f(F2[(size_t)p2.y * D2 + l]);
        float v3 = bu2f(F2[(size_t)p3.y * D2 + l]);
        aF0 = fmaf(__uint_as_float(p0.x), v0, aF0);
        aF1 = fmaf(__uint_as_float(p1.x), v1, aF1);
        aF2 = fmaf(__uint_as_float(p2.x), v2, aF2);
        aF3 = fmaf(__uint_as_float(p3.x), v3, aF3);
    }
    for (; e < dcap; ++e) {
        uint2 p = *(const uint2*)&sWS[nb * 64 + 2 * e];
        aF0 = fmaf(__uint_as_float(p.x), bu2f(F2[(size_t)p.y * D2 + l]), aF0);
    }
    if (dr > CAP) {                            // rare overflow edges (redundant w, tiny count)
        int novf = *ovfc;
        for (int p = 0; p < novf; ++p) {
            int2 o = ovf[p];
            if (o.x == i) {
                float wA = __expf(lrelu(EL2[o.y] + eri));
                S += wA;
                aF0 = fmaf(wA, bu2f(F2[(size_t)o.y * D2 + l]), aF0);
            }
        }
    }
    float aF = (aF0 + aF1) + (aF2 + aF3);
    float inv = S > 0.0f ? 1.0f / S : 0.0f;

    float h2 = fmaxf((aF * inv + RS2[(size_t)i * D2 + l]) * sSc2[l] + sRc2[l], 0.0f);
    RS2[(size_t)i * D2 + l] = h2;

    sH2[nb * D2 + l] = h2;
    float ac0 = 0.0f, ac1 = 0.0f, ac2 = 0.0f, ac3 = 0.0f;
#pragma unroll
    for (int d = 0; d < D2; ++d) {
        float h = sH2[nb * D2 + d];
        const float* wr = &sWd1[d * C1 + l];
        ac0 = fmaf(h, wr[0],  ac0);
        ac1 = fmaf(h, wr[32], ac1);
        ac2 = fmaf(h, wr[64], ac2);
        ac3 = fmaf(h, wr[96], ac3);
    }
    float rec = fmaxf(ac0 * sSd[l]      + sRd[l],      0.0f) * sWd2[l]
              + fmaxf(ac1 * sSd[l + 32] + sRd[l + 32], 0.0f) * sWd2[l + 32]
              + fmaxf(ac2 * sSd[l + 64] + sRd[l + 64], 0.0f) * sWd2[l + 64]
              + fmaxf(ac3 * sSd[l + 96] + sRd[l + 96], 0.0f) * sWd2[l + 96];
#pragma unroll
    for (int m = 16; m >= 1; m >>= 1) rec += __shfl_xor(rec, m);
    if (l == 0) out[NG * D2 + i] = rec + ldw(bd2, 0, bf);
}

// ---------------- graph mean pool: 32 rows x float4 ----------------
__global__ __launch_bounds__(256) void k_pool2(const int* __restrict__ gid,
                                               const float* __restrict__ H2,
                                               float* __restrict__ out) {
    __shared__ int sLo, sHi;
    __shared__ float sAcc[32 * 32];
    int g = blockIdx.x;
    int t = threadIdx.x;
    if (t == 0) {
        int lo = 0, hi = NN;
        while (lo < hi) { int m = (lo + hi) >> 1; if (gid[m] < g) lo = m + 1; else hi = m; }
        sLo = lo;
        lo = 0; hi = NN;
        while (lo < hi) { int m = (lo + hi) >> 1; if (gid[m] < g + 1) lo = m + 1; else hi = m; }
        sHi = lo;
    }
    __syncthreads();
    int lo = sLo, hi = sHi;
    int q = t & 7;
    int row = t >> 3;
    float4 acc = make_float4(0.f, 0.f, 0.f, 0.f);
    for (int i = lo + row; i < hi; i += 32) {
        float4 v = ((const float4*)&H2[(size_t)i * D2])[q];
        acc.x += v.x; acc.y += v.y; acc.z += v.z; acc.w += v.w;
    }
    *(float4*)&sAcc[row * 32 + 4 * q] = acc;
    __syncthreads();
    if (t < 32) {
        float a = 0.0f;
        for (int r = 0; r < 32; ++r) a += sAcc[r * 32 + t];
        float c = (float)(hi - lo);
        out[g * D2 + t] = a / fmaxf(c, 1.0f);
    }
}

extern "C" void kernel_launch(void* const* d_in, const int* in_sizes, int n_in,
                              void* d_out, int out_size, void* d_ws, size_t ws_size,
                              hipStream_t stream) {
    const void* feat = d_in[0];
    const void* W1 = d_in[1];  const void* al1 = d_in[2];  const void* ar1 = d_in[3];
    const void* res1 = d_in[4]; const void* b1 = d_in[5];
    const void* g1g = d_in[6]; const void* g1b = d_in[7];
    const void* g1m = d_in[8]; const void* g1v = d_in[9];
    const void* W2 = d_in[10]; const void* al2 = d_in[11]; const void* ar2 = d_in[12];
    const void* res2 = d_in[13]; const void* b2v = d_in[14];
    const void* g2g = d_in[15]; const void* g2b = d_in[16];
    const void* g2m = d_in[17]; const void* g2v = d_in[18];
    const void* Wd1 = d_in[19]; const void* bd1 = d_in[20];
    const void* gdg = d_in[21]; const void* gdb = d_in[22];
    const void* gdm = d_in[23]; const void* gdv = d_in[24];
    const void* Wd2 = d_in[25]; const void* bd2 = d_in[26];
    const int* src = (const int*)d_in[27];
    const int* dst = (const int*)d_in[28];
    const int* gid = (const int*)d_in[29];

    unsigned int* wsu = (unsigned int*)d_ws;
    int* degp   = (int*)(wsu + UO_DEGP);
    int* ovfc   = (int*)(wsu + UO_OVFC);
    int* flag   = (int*)(wsu + UO_FLAG);
    float* cst  = (float*)(wsu + UO_CST);
    unsigned short* esrc2 = (unsigned short*)(wsu + UO_ESRC2);
    int2* ovf   = (int2*)(wsu + UO_OVF);
    float* fcan = (float*)(wsu + UO_FCAN);
    unsigned short* F2 = (unsigned short*)(wsu + UO_F2);
    float* RS2  = (float*)(wsu + UO_RS2);
    float* EL2  = (float*)(wsu + UO_EL2);
    float* ER2  = (float*)(wsu + UO_ER2);

    hipMemsetAsync(d_ws, 0, (size_t)ZERO_UNITS * 4, stream);

    k_prep<<<NCH * 8, 256, 0, stream>>>(feat, dst, src, fcan, degp,
                                        esrc2, ovf, ovfc,
                                        W1, al1, ar1, res1, b1,
                                        g1g, g1b, g1m, g1v,
                                        b2v, g2g, g2b, g2m, g2v,
                                        bd1, gdg, gdb, gdm, gdv,
                                        flag, cst);

    k_layer1<<<(NN + 31) / 32, 256, 0, stream>>>(fcan, W2, res2, al2, ar2, flag, cst,
                                                 degp, esrc2, ovf, ovfc,
                                                 F2, RS2, EL2, ER2);

    k_final<<<(NN * 32) / 256, 256, 0, stream>>>(Wd1, Wd2, bd2, flag, cst,
                                                 degp, esrc2, ovf, ovfc,
                                                 F2, RS2, EL2, ER2,
                                                 (float*)d_out);

    k_pool2<<<NG, 256, 0, stream>>>(gid, RS2, (float*)d_out);
}

// Round 23
// 243.248 us; speedup vs baseline: 1.2120x; 1.0095x over previous
//
#include <hip/hip_runtime.h>
#include <hip/hip_bf16.h>
#include <hip/hip_fp16.h>

#define NN 50000
#define NE 800000
#define NG 64
#define C1 128    // H1*D1
#define D2 32
#define CAP 32    // capped slots per node; overflow handled exactly via ovf buffer
#define RNG 6250  // NN/8: dst-range width per XCD partition
#define NCH 391   // ceil(NE/2048) edge chunks
#define BN_EPS 1e-5f

// ---- constant-block layout (float offsets inside cst) ----
#define CST_A   0
#define CST_B   2
#define CST_P   4
#define CST_Q   132
#define CST_R   260
#define CST_SC2 388
#define CST_RC2 420
#define CST_SD  452
#define CST_RD  580
#define CST_N   1024

// ---- workspace layout (4-byte-unit offsets inside d_ws), ~23 MiB (ws is 256 MB) ----
#define UO_DEGP  0                        // int[16*NN] padded: one counter per 64B line (zeroed)
#define UO_OVFC  800000                   // int[1]   (zeroed)
#define ZERO_UNITS 800004
#define UO_FLAG  800004                   // int[1]
#define UO_CST   800008                   // float[CST_N]
#define UO_ESRC2 801040                   // ushort[CAP*NN] padded edge table (64B-aligned rows)
#define UO_OVF   1601040                  // int2[NE] overflow (dst,src)
#define UO_FCAN  3201040                  // float[NN]
#define UO_F2    3251040                  // ushort[D2*NN] bf16 (16B aligned)
#define UO_RS2   4051040                  // float[D2*NN]; overwritten with h2 by k_final
#define UO_EL2   5651040                  // float[NN]
#define UO_ER2   5701040                  // float[NN]
#define UO_END   5751040

typedef _Float16 h2vec __attribute__((ext_vector_type(2)));

__device__ __forceinline__ float lrelu(float x) { return fmaxf(x, 0.2f * x); }
__device__ __forceinline__ float bu2f(unsigned int u) {
    union { unsigned int i; float f; } v; v.i = (u & 0xFFFFu) << 16; return v.f;
}
__device__ __forceinline__ unsigned short f2bu(float f) {
    union { float f; unsigned int i; } v; v.f = f;
    unsigned int r = v.i + 0x7FFFu + ((v.i >> 16) & 1u);
    return (unsigned short)(r >> 16);
}
// pack two floats as f16 pair in one uint
__device__ __forceinline__ unsigned int packh2(float a, float b) {
    h2vec h; h.x = (_Float16)a; h.y = (_Float16)b;
    union { h2vec h; unsigned int u; } v; v.h = h; return v.u;
}
__device__ __forceinline__ h2vec as_h2(unsigned int u) {
    union { unsigned int u; h2vec h; } v; v.u = u; return v.h;
}
__device__ __forceinline__ float ldw(const void* p, int i, int bf) {
    return bf ? bu2f(((const unsigned short*)p)[i]) : ((const float*)p)[i];
}
__device__ __forceinline__ int sniff64(const unsigned int* fw, int l) {
    int cnt = 0;
    for (int j = l; j < 256; j += 64) {
        unsigned int b = (fw[j] >> 8) & 0x7Fu;
        cnt += (b >= 0x3Au && b <= 0x41u) ? 1 : 0;
    }
#pragma unroll
    for (int m = 32; m >= 1; m >>= 1) cnt += __shfl_xor(cnt, m);
    return (cnt > 128) ? 1 : 0;
}

// ---------------- edge-table build, XCD-range partitioned (BLOCKED mapping) ----------------
// grid = NCH*8; block b: dst range b/NCH, edge chunk b%NCH. Hypothesis: dispatcher assigns
// contiguous block chunks per XCD, so blocked range mapping keeps each XCD on its 1/8 of
// esrc2/degp (interleaved b&7 mapping only gave 1.7x traffic cut -> round-robin disproven).
__global__ void k_prep(const void* __restrict__ feat, const int* __restrict__ dst,
                       const int* __restrict__ src,
                       float* __restrict__ fcan, int* __restrict__ degp,
                       unsigned short* __restrict__ esrc2,
                       int2* __restrict__ ovf, int* __restrict__ ovfc,
                       const void* W1, const void* al1, const void* ar1,
                       const void* res1, const void* b1,
                       const void* g1g, const void* g1b, const void* g1m, const void* g1v,
                       const void* b2v, const void* g2g, const void* g2b,
                       const void* g2m, const void* g2v,
                       const void* bd1, const void* gdg, const void* gdb,
                       const void* gdm, const void* gdv,
                       int* __restrict__ flag, float* __restrict__ cst) {
    __shared__ int sBf;
    int t = threadIdx.x;
    if (t < 64) {
        int bf = sniff64((const unsigned int*)feat, t);
        if (t == 0) sBf = bf;
    }
    __syncthreads();
    int bf = sBf;
    int r = blockIdx.x / NCH;   // BLOCKED range mapping (was blockIdx & 7)
    int c = blockIdx.x % NCH;

    if (blockIdx.x == 0) {             // fold tiny weights into fp32 constants
        if (t == 0) *flag = bf;
        if (t < 128) {
            if (t < 2) {
                float a = 0.0f, b = 0.0f;
                for (int d = 0; d < 64; ++d) {
                    float w = ldw(W1, t * 64 + d, bf);
                    a += w * ldw(al1, t * 64 + d, bf);
                    b += w * ldw(ar1, t * 64 + d, bf);
                }
                cst[CST_A + t] = a;
                cst[CST_B + t] = b;
            }
            {
                float sc = rsqrtf(ldw(g1v, t, bf) + BN_EPS) * ldw(g1g, t, bf);
                cst[CST_P + t] = ldw(W1, t, bf) * sc;
                cst[CST_Q + t] = ldw(res1, t, bf) * sc;
                cst[CST_R + t] = (ldw(b1, t, bf) - ldw(g1m, t, bf)) * sc + ldw(g1b, t, bf);
            }
            if (t < D2) {
                float sc = rsqrtf(ldw(g2v, t, bf) + BN_EPS) * ldw(g2g, t, bf);
                cst[CST_SC2 + t] = sc;
                cst[CST_RC2 + t] = (ldw(b2v, t, bf) - ldw(g2m, t, bf)) * sc + ldw(g2b, t, bf);
            }
            {
                float sc = rsqrtf(ldw(gdv, t, bf) + BN_EPS) * ldw(gdg, t, bf);
                cst[CST_SD + t] = sc;
                cst[CST_RD + t] = (ldw(bd1, t, bf) - ldw(gdm, t, bf)) * sc + ldw(gdb, t, bf);
            }
        }
    }

    int lo = r * RNG, hi = lo + RNG;
#pragma unroll
    for (int j = 0; j < 8; ++j) {
        int k = c * 2048 + j * 256 + t;
        if (k < NE) {
            int d = dst[k];
            if (d >= lo && d < hi) {
                int slot = atomicAdd(&degp[d << 4], 1);
                if (slot < CAP) {
                    esrc2[d * CAP + slot] = (unsigned short)src[k];
                } else {
                    int p = atomicAdd(ovfc, 1);    // rare
                    ovf[p] = make_int2(d, src[k]);
                }
            }
        }
        if (r == 0 && k < NN) fcan[k] = ldw(feat, k, bf);
    }
}

// ---------------- layer-1: 32 nodes/block; f16-pair LDS + v_dot2_f32_f16 projection ----------------
__global__ __launch_bounds__(256) void k_layer1(
        const float* __restrict__ fcan, const void* W2, const void* res2,
        const void* al2, const void* ar2,
        const int* __restrict__ flag, const float* __restrict__ cst,
        const int* __restrict__ degp, const unsigned short* __restrict__ esrc2,
        const int2* __restrict__ ovf, const int* __restrict__ ovfc,
        unsigned short* __restrict__ F2, float* __restrict__ RS2,
        float* __restrict__ EL2, float* __restrict__ ER2) {
    __shared__ unsigned int sW2pk[32 * 66];  // [l][cw], (c,c+64) f16 pairs
    __shared__ unsigned int sR2pk[32 * 66];
    __shared__ unsigned int sH1pk[32 * 66];
    __shared__ float sP[C1], sQ[C1], sR[C1];
    __shared__ float sAl[D2], sAr[D2];
    int t = threadIdx.x;
    int bf = *flag;
    for (int u = t; u < 2048; u += 256) {
        int cw = u >> 5, l2 = u & 31;
        sW2pk[l2 * 66 + cw] = packh2(ldw(W2, cw * D2 + l2, bf),
                                     ldw(W2, (cw + 64) * D2 + l2, bf));
        sR2pk[l2 * 66 + cw] = packh2(ldw(res2, cw * D2 + l2, bf),
                                     ldw(res2, (cw + 64) * D2 + l2, bf));
    }
    if (t < C1) { sP[t] = cst[CST_P + t]; sQ[t] = cst[CST_Q + t]; sR[t] = cst[CST_R + t]; }
    if (t < D2) { sAl[t] = ldw(al2, t, bf); sAr[t] = ldw(ar2, t, bf); }
    __syncthreads();

    int l = t & 31;
    int g = t >> 5;
    int base = blockIdx.x * 32;
    float A0 = cst[CST_A + 0], A1 = cst[CST_A + 1];
    float B0 = cst[CST_B + 0], B1 = cst[CST_B + 1];

    int dcap[4], draw[4];
    float fiK[4];
#pragma unroll
    for (int k = 0; k < 4; ++k) {
        int i = base + g * 4 + k;
        if (i < NN) {
            draw[k] = degp[i << 4];
            dcap[k] = draw[k] < CAP ? draw[k] : CAP;
            fiK[k] = fcan[i];
        } else { draw[k] = 0; dcap[k] = 0; fiK[k] = 0.0f; }
    }
    float S0[4], S1[4], N0[4], N1[4];
#pragma unroll
    for (int k = 0; k < 4; ++k) { S0[k] = S1[k] = N0[k] = N1[k] = 0.0f; }
    int sA[4];
#pragma unroll
    for (int k = 0; k < 4; ++k)
        sA[k] = (l < dcap[k]) ? (int)esrc2[(base + g * 4 + k) * CAP + l] : 0;
    float fA[4];
#pragma unroll
    for (int k = 0; k < 4; ++k) fA[k] = fcan[sA[k]];
#pragma unroll
    for (int k = 0; k < 4; ++k) {
        if (l < dcap[k]) {
            float w0 = __expf(lrelu(A0 * fA[k] + B0 * fiK[k]));
            float w1 = __expf(lrelu(A1 * fA[k] + B1 * fiK[k]));
            S0[k] += w0; N0[k] += w0 * fA[k];
            S1[k] += w1; N1[k] += w1 * fA[k];
        }
    }
    // rare overflow edges (deg > CAP)
#pragma unroll
    for (int k = 0; k < 4; ++k) {
        if (draw[k] > CAP) {
            int i = base + g * 4 + k;
            int novf = *ovfc;
            for (int p = l; p < novf; p += 32) {
                int2 o = ovf[p];
                if (o.x == i) {
                    float fs = fcan[o.y];
                    float w0 = __expf(lrelu(A0 * fs + B0 * fiK[k]));
                    float w1 = __expf(lrelu(A1 * fs + B1 * fiK[k]));
                    S0[k] += w0; N0[k] += w0 * fs;
                    S1[k] += w1; N1[k] += w1 * fs;
                }
            }
        }
    }
#pragma unroll
    for (int m = 16; m >= 1; m >>= 1) {
#pragma unroll
        for (int k = 0; k < 4; ++k) {
            S0[k] += __shfl_xor(S0[k], m); N0[k] += __shfl_xor(N0[k], m);
            S1[k] += __shfl_xor(S1[k], m); N1[k] += __shfl_xor(N1[k], m);
        }
    }
#pragma unroll
    for (int k = 0; k < 4; ++k) {
        int slot = g * 4 + k;
        float T0 = S0[k] > 0.0f ? N0[k] / S0[k] : 0.0f;
        float T1 = S1[k] > 0.0f ? N1[k] / S1[k] : 0.0f;
        float h0  = fmaxf(sP[l]      * T0 + sQ[l]      * fiK[k] + sR[l],      0.0f);
        float h1v = fmaxf(sP[l + 32] * T0 + sQ[l + 32] * fiK[k] + sR[l + 32], 0.0f);
        float h2v = fmaxf(sP[l + 64] * T1 + sQ[l + 64] * fiK[k] + sR[l + 64], 0.0f);
        float h3v = fmaxf(sP[l + 96] * T1 + sQ[l + 96] * fiK[k] + sR[l + 96], 0.0f);
        sH1pk[slot * 66 + l]      = packh2(h0,  h2v);   // (c, c+64) f16 pair
        sH1pk[slot * 66 + l + 32] = packh2(h1v, h3v);
    }
    __syncthreads();

    // --- phase 2: v_dot2_f32_f16 — one inst per (c,c+64) pair, fp32 accumulate
    int w = t >> 6;
    int half = (t >> 5) & 1;
    int nb0 = w * 8 + half * 4;
    float aF[4] = {0.f, 0.f, 0.f, 0.f}, aR[4] = {0.f, 0.f, 0.f, 0.f};
    for (int cw = 0; cw < 64; cw += 2) {
        uint2 wq = *(const uint2*)&sW2pk[l * 66 + cw];
        uint2 rq = *(const uint2*)&sR2pk[l * 66 + cw];
#pragma unroll
        for (int n = 0; n < 4; ++n) {
            uint2 hq = *(const uint2*)&sH1pk[(nb0 + n) * 66 + cw];   // broadcast
            aF[n] = __builtin_amdgcn_fdot2(as_h2(hq.x), as_h2(wq.x),
                    __builtin_amdgcn_fdot2(as_h2(hq.y), as_h2(wq.y), aF[n], false), false);
            aR[n] = __builtin_amdgcn_fdot2(as_h2(hq.x), as_h2(rq.x),
                    __builtin_amdgcn_fdot2(as_h2(hq.y), as_h2(rq.y), aR[n], false), false);
        }
    }
#pragma unroll
    for (int n = 0; n < 4; ++n) {
        int i = base + nb0 + n;
        if (i < NN) {
            float elp = aF[n] * sAl[l], erp = aF[n] * sAr[l];
#pragma unroll
            for (int m = 16; m >= 1; m >>= 1) {
                elp += __shfl_xor(elp, m);
                erp += __shfl_xor(erp, m);
            }
            if (l == 0) { EL2[i] = elp; ER2[i] = erp; }
            F2[(size_t)i * D2 + l]  = f2bu(aF[n]);
            RS2[(size_t)i * D2 + l] = aR[n];
        }
    }
}

// ---------------- layer-2 gather: per-lane w (exp once/edge) + LDS (w,s) broadcast ----------------
__global__ __launch_bounds__(256) void k_final(
        const void* Wd1, const void* Wd2, const void* bd2,
        const int* __restrict__ flag, const float* __restrict__ cst,
        const int* __restrict__ degp, const unsigned short* __restrict__ esrc2,
        const int2* __restrict__ ovf, const int* __restrict__ ovfc,
        const unsigned short* __restrict__ F2, float* __restrict__ RS2,
        const float* __restrict__ EL2, const float* __restrict__ ER2,
        float* __restrict__ out) {
    __shared__ float sWd1[C1 * D2];
    __shared__ float sWd2[C1];
    __shared__ float sSd[C1], sRd[C1];
    __shared__ float sSc2[D2], sRc2[D2];
    __shared__ float sH2[8 * D2];
    __shared__ unsigned int sWS[8 * 64];  // per-group (w,s) pairs
    int t = threadIdx.x;
    int bf = *flag;
    for (int u = t; u < C1 * D2; u += 256) sWd1[u] = ldw(Wd1, u, bf);
    for (int u = t; u < C1; u += 256) {
        sWd2[u] = ldw(Wd2, u, bf);
        sSd[u] = cst[CST_SD + u]; sRd[u] = cst[CST_RD + u];
    }
    if (t < D2) { sSc2[t] = cst[CST_SC2 + t]; sRc2[t] = cst[CST_RC2 + t]; }
    __syncthreads();

    int i = (blockIdx.x * 256 + t) >> 5;
    int l = t & 31;
    int nb = t >> 5;

    float eri = ER2[i];
    int dr = degp[i << 4];
    int dcap = dr < CAP ? dr : CAP;
    const unsigned short* row = &esrc2[i * CAP];

    // --- per-lane w: lane l owns edge l (exp computed ONCE per edge)
    int sMy = 0; float wMy = 0.0f;
    if (l < dcap) {
        sMy = (int)row[l];
        wMy = __expf(lrelu(EL2[sMy] + eri));
    }
    float S = wMy;
#pragma unroll
    for (int m = 16; m >= 1; m >>= 1) S += __shfl_xor(S, m);
    sWS[nb * 64 + 2 * l]     = __float_as_uint(wMy);
    sWS[nb * 64 + 2 * l + 1] = (unsigned int)sMy;

    float aF0 = 0.f, aF1 = 0.f, aF2 = 0.f, aF3 = 0.f;
    int e = 0;
    for (; e + 3 < dcap; e += 4) {
        uint2 p0 = *(const uint2*)&sWS[nb * 64 + 2 * e];
        uint2 p1 = *(const uint2*)&sWS[nb * 64 + 2 * (e + 1)];
        uint2 p2 = *(const uint2*)&sWS[nb * 64 + 2 * (e + 2)];
        uint2 p3 = *(const uint2*)&sWS[nb * 64 + 2 * (e + 3)];
        float v0 = bu2f(F2[(size_t)p0.y * D2 + l]);
        float v1 = bu2f(F2[(size_t)p1.y * D2 + l]);
        float v2 = bu2f(F2[(size_t)p2.y * D2 + l]);
        float v3 = bu2f(F2[(size_t)p3.y * D2 + l]);
        aF0 = fmaf(__uint_as_float(p0.x), v0, aF0);
        aF1 = fmaf(__uint_as_float(p1.x), v1, aF1);
        aF2 = fmaf(__uint_as_float(p2.x), v2, aF2);
        aF3 = fmaf(__uint_as_float(p3.x), v3, aF3);
    }
    for (; e < dcap; ++e) {
        uint2 p = *(const uint2*)&sWS[nb * 64 + 2 * e];
        aF0 = fmaf(__uint_as_float(p.x), bu2f(F2[(size_t)p.y * D2 + l]), aF0);
    }
    if (dr > CAP) {
        int novf = *ovfc;
        for (int p = 0; p < novf; ++p) {
            int2 o = ovf[p];
            if (o.x == i) {
                float wA = __expf(lrelu(EL2[o.y] + eri));
                S += wA;
                aF0 = fmaf(wA, bu2f(F2[(size_t)o.y * D2 + l]), aF0);
            }
        }
    }
    float aF = (aF0 + aF1) + (aF2 + aF3);
    float inv = S > 0.0f ? 1.0f / S : 0.0f;

    float h2 = fmaxf((aF * inv + RS2[(size_t)i * D2 + l]) * sSc2[l] + sRc2[l], 0.0f);
    RS2[(size_t)i * D2 + l] = h2;

    sH2[nb * D2 + l] = h2;
    float ac0 = 0.0f, ac1 = 0.0f, ac2 = 0.0f, ac3 = 0.0f;
#pragma unroll
    for (int d = 0; d < D2; ++d) {
        float h = sH2[nb * D2 + d];
        const float* wr = &sWd1[d * C1 + l];
        ac0 = fmaf(h, wr[0],  ac0);
        ac1 = fmaf(h, wr[32], ac1);
        ac2 = fmaf(h, wr[64], ac2);
        ac3 = fmaf(h, wr[96], ac3);
    }
    float rec = fmaxf(ac0 * sSd[l]      + sRd[l],      0.0f) * sWd2[l]
              + fmaxf(ac1 * sSd[l + 32] + sRd[l + 32], 0.0f) * sWd2[l + 32]
              + fmaxf(ac2 * sSd[l + 64] + sRd[l + 64], 0.0f) * sWd2[l + 64]
              + fmaxf(ac3 * sSd[l + 96] + sRd[l + 96], 0.0f) * sWd2[l + 96];
#pragma unroll
    for (int m = 16; m >= 1; m >>= 1) rec += __shfl_xor(rec, m);
    if (l == 0) out[NG * D2 + i] = rec + ldw(bd2, 0, bf);
}

// ---------------- graph mean pool: 32 rows x float4 ----------------
__global__ __launch_bounds__(256) void k_pool2(const int* __restrict__ gid,
                                               const float* __restrict__ H2,
                                               float* __restrict__ out) {
    __shared__ int sLo, sHi;
    __shared__ float sAcc[32 * 32];
    int g = blockIdx.x;
    int t = threadIdx.x;
    if (t == 0) {
        int lo = 0, hi = NN;
        while (lo < hi) { int m = (lo + hi) >> 1; if (gid[m] < g) lo = m + 1; else hi = m; }
        sLo = lo;
        lo = 0; hi = NN;
        while (lo < hi) { int m = (lo + hi) >> 1; if (gid[m] < g + 1) lo = m + 1; else hi = m; }
        sHi = lo;
    }
    __syncthreads();
    int lo = sLo, hi = sHi;
    int q = t & 7;
    int row = t >> 3;
    float4 acc = make_float4(0.f, 0.f, 0.f, 0.f);
    for (int i = lo + row; i < hi; i += 32) {
        float4 v = ((const float4*)&H2[(size_t)i * D2])[q];
        acc.x += v.x; acc.y += v.y; acc.z += v.z; acc.w += v.w;
    }
    *(float4*)&sAcc[row * 32 + 4 * q] = acc;
    __syncthreads();
    if (t < 32) {
        float a = 0.0f;
        for (int r = 0; r < 32; ++r) a += sAcc[r * 32 + t];
        float c = (float)(hi - lo);
        out[g * D2 + t] = a / fmaxf(c, 1.0f);
    }
}

extern "C" void kernel_launch(void* const* d_in, const int* in_sizes, int n_in,
                              void* d_out, int out_size, void* d_ws, size_t ws_size,
                              hipStream_t stream) {
    const void* feat = d_in[0];
    const void* W1 = d_in[1];  const void* al1 = d_in[2];  const void* ar1 = d_in[3];
    const void* res1 = d_in[4]; const void* b1 = d_in[5];
    const void* g1g = d_in[6]; const void* g1b = d_in[7];
    const void* g1m = d_in[8]; const void* g1v = d_in[9];
    const void* W2 = d_in[10]; const void* al2 = d_in[11]; const void* ar2 = d_in[12];
    const void* res2 = d_in[13]; const void* b2v = d_in[14];
    const void* g2g = d_in[15]; const void* g2b = d_in[16];
    const void* g2m = d_in[17]; const void* g2v = d_in[18];
    const void* Wd1 = d_in[19]; const void* bd1 = d_in[20];
    const void* gdg = d_in[21]; const void* gdb = d_in[22];
    const void* gdm = d_in[23]; const void* gdv = d_in[24];
    const void* Wd2 = d_in[25]; const void* bd2 = d_in[26];
    const int* src = (const int*)d_in[27];
    const int* dst = (const int*)d_in[28];
    const int* gid = (const int*)d_in[29];

    unsigned int* wsu = (unsigned int*)d_ws;
    int* degp   = (int*)(wsu + UO_DEGP);
    int* ovfc   = (int*)(wsu + UO_OVFC);
    int* flag   = (int*)(wsu + UO_FLAG);
    float* cst  = (float*)(wsu + UO_CST);
    unsigned short* esrc2 = (unsigned short*)(wsu + UO_ESRC2);
    int2* ovf   = (int2*)(wsu + UO_OVF);
    float* fcan = (float*)(wsu + UO_FCAN);
    unsigned short* F2 = (unsigned short*)(wsu + UO_F2);
    float* RS2  = (float*)(wsu + UO_RS2);
    float* EL2  = (float*)(wsu + UO_EL2);
    float* ER2  = (float*)(wsu + UO_ER2);

    hipMemsetAsync(d_ws, 0, (size_t)ZERO_UNITS * 4, stream);

    k_prep<<<NCH * 8, 256, 0, stream>>>(feat, dst, src, fcan, degp,
                                        esrc2, ovf, ovfc,
                                        W1, al1, ar1, res1, b1,
                                        g1g, g1b, g1m, g1v,
                                        b2v, g2g, g2b, g2m, g2v,
                                        bd1, gdg, gdb, gdm, gdv,
                                        flag, cst);

    k_layer1<<<(NN + 31) / 32, 256, 0, stream>>>(fcan, W2, res2, al2, ar2, flag, cst,
                                                 degp, esrc2, ovf, ovfc,
                                                 F2, RS2, EL2, ER2);

    k_final<<<(NN * 32) / 256, 256, 0, stream>>>(Wd1, Wd2, bd2, flag, cst,
                                                 degp, esrc2, ovf, ovfc,
                                                 F2, RS2, EL2, ER2,
                                                 (float*)d_out);

    k_pool2<<<NG, 256, 0, stream>>>(gid, RS2, (float*)d_out);
}